// Round 1
// baseline (4228.711 us; speedup 1.0000x reference)
//
#include <hip/hip_runtime.h>
#include <hip/hip_bf16.h>
#include <math.h>

// ---- constants ----
#define BB    32
#define DD    768
#define LL    12
#define HH    12
#define NN    196
#define DHH   64
#define FFF   3072
#define MM    (BB * NN)      // 6272 tokens
#define BHH   (BB * HH)      // 384

typedef float  floatx4 __attribute__((ext_vector_type(4)));
typedef __bf16 bf16x8  __attribute__((ext_vector_type(8)));

#define DEV __device__ __forceinline__

DEV unsigned short bf16u(float v) {
  __hip_bfloat16 h = __float2bfloat16(v);
  return __builtin_bit_cast(unsigned short, h);
}

DEV floatx4 mfma_bf16(bf16x8 a, bf16x8 b, floatx4 c) {
  return __builtin_amdgcn_mfma_f32_16x16x32_bf16(a, b, c, 0, 0, 0);
}

DEV void gl2lds16(const void* g, void* l) {
  __builtin_amdgcn_global_load_lds(
      (const __attribute__((address_space(1))) void*)g,
      (__attribute__((address_space(3))) void*)l, 16, 0, 0);
}

// ---- fp32 -> bf16 conversion (vectorized) ----
__global__ __launch_bounds__(256) void cvt4_k(const float4* __restrict__ in,
                                              ushort4* __restrict__ out, int n4) {
  int i = blockIdx.x * 256 + threadIdx.x;
  if (i < n4) {
    float4 v = in[i];
    ushort4 o;
    o.x = bf16u(v.x); o.y = bf16u(v.y); o.z = bf16u(v.z); o.w = bf16u(v.w);
    out[i] = o;
  }
}

// ---- im2col for patch embed: x (32,3,224,224) -> A (6272, 768) bf16 ----
__global__ __launch_bounds__(256) void im2col_k(const float* __restrict__ x,
                                                unsigned short* __restrict__ A) {
  int idx = blockIdx.x * 256 + threadIdx.x;      // grid covers 6272*768 exactly
  int col = idx % DD;
  int token = idx / DD;
  int b = token / NN, p = token % NN;
  int pr = p / 14, pc = p % 14;
  int c = col >> 8, rm = col & 255, i = rm >> 4, j = rm & 15;
  float v = x[(((size_t)b * 3 + c) * 224 + pr * 16 + i) * 224 + pc * 16 + j];
  A[idx] = bf16u(v);
}

// ---- LayerNorm: h fp32 (M,768) -> out (bf16 or fp32) ----
template <int F32OUT>
__global__ __launch_bounds__(256) void ln_k(const float* __restrict__ x,
                                            const float* __restrict__ w,
                                            const float* __restrict__ bb,
                                            void* __restrict__ outp) {
  const int token = blockIdx.x, tid = threadIdx.x;
  const float* xr = x + (size_t)token * DD;
  float v0 = xr[tid], v1 = xr[tid + 256], v2 = xr[tid + 512];
  float s = v0 + v1 + v2;
  float ss = v0 * v0 + v1 * v1 + v2 * v2;
#pragma unroll
  for (int off = 32; off; off >>= 1) {
    s += __shfl_down(s, off);
    ss += __shfl_down(ss, off);
  }
  __shared__ float rs[4], rq[4];
  if ((tid & 63) == 0) { rs[tid >> 6] = s; rq[tid >> 6] = ss; }
  __syncthreads();
  float tot = rs[0] + rs[1] + rs[2] + rs[3];
  float tq  = rq[0] + rq[1] + rq[2] + rq[3];
  const float mean = tot * (1.0f / 768.0f);
  const float var  = tq * (1.0f / 768.0f) - mean * mean;
  const float rstd = rsqrtf(var + 1e-5f);
#pragma unroll
  for (int t = 0; t < 3; t++) {
    int col = tid + t * 256;
    float xv = (t == 0) ? v0 : (t == 1 ? v1 : v2);
    float yv = (xv - mean) * rstd * w[col] + bb[col];
    if (F32OUT) ((float*)outp)[(size_t)token * DD + col] = yv;
    else        ((unsigned short*)outp)[(size_t)token * DD + col] = bf16u(yv);
  }
}

// LDS k-chunk XOR swizzle (R3, verified: conflicts -> 0): LDS slot (row,s)
// holds global k-chunk s ^ ((row>>1)&3); staging permutes the GLOBAL source,
// reads apply the same XOR.

// ---- GEMM 128x128, double-buffered LDS ----
// MODE 0: out bf16 = acc + bias
// MODE 3: out bf16 = gelu(acc + bias)
template <int MODE>
__global__ __launch_bounds__(256, 4) void gemm_bt(
    const unsigned short* __restrict__ A, const unsigned short* __restrict__ W,
    const float* __restrict__ bias, void* __restrict__ outp, int K, int Nn) {
  __shared__ unsigned short As[2][128 * 32];
  __shared__ unsigned short Bs[2][128 * 32];
  const int tid = threadIdx.x;
  const int wave = tid >> 6, lane = tid & 63;
  const int tm = blockIdx.y * 128, tn = blockIdx.x * 128;
  const int wm = (wave >> 1) * 64, wn = (wave & 1) * 64;
  const int lr = lane & 15, kq = lane >> 4;
  const int sw = (lr >> 1) & 3;
  const int koff = (kq ^ sw) * 8;
  const int c0 = tid, c1 = tid + 256;
  const int r0 = c0 >> 2, r1 = c1 >> 2;
  const int kc0 = ((c0 & 3) ^ ((r0 >> 1) & 3)) * 8;
  const int kc1 = ((c1 & 3) ^ ((r1 >> 1) & 3)) * 8;
  const size_t ga0 = (size_t)(tm + r0) * K + kc0;
  const size_t ga1 = (size_t)(tm + r1) * K + kc1;
  const size_t gb0 = (size_t)(tn + r0) * K + kc0;
  const size_t gb1 = (size_t)(tn + r1) * K + kc1;
  floatx4 acc[4][4] = {};
  auto stage = [&](int buf, int k0) {
    gl2lds16(A + ga0 + k0, &As[buf][c0 * 8]);
    gl2lds16(A + ga1 + k0, &As[buf][c1 * 8]);
    gl2lds16(W + gb0 + k0, &Bs[buf][c0 * 8]);
    gl2lds16(W + gb1 + k0, &Bs[buf][c1 * 8]);
  };
  const int nk = K >> 5;
  stage(0, 0);
  for (int it = 0; it < nk; it++) {
    const int cur = it & 1;
    __syncthreads();                       // drains stage(cur) (issued last iter)
    if (it + 1 < nk) stage(cur ^ 1, (it + 1) << 5);
    bf16x8 af[4], bq[4];
#pragma unroll
    for (int mi = 0; mi < 4; mi++)
      af[mi] = *(const bf16x8*)&As[cur][(wm + mi * 16 + lr) * 32 + koff];
#pragma unroll
    for (int ni = 0; ni < 4; ni++)
      bq[ni] = *(const bf16x8*)&Bs[cur][(wn + ni * 16 + lr) * 32 + koff];
#pragma unroll
    for (int mi = 0; mi < 4; mi++)
#pragma unroll
      for (int ni = 0; ni < 4; ni++)
        acc[mi][ni] = mfma_bf16(af[mi], bq[ni], acc[mi][ni]);
  }
  const int rbase = tm + wm + (lane >> 4) * 4;
  const int cbase = tn + wn + lr;
#pragma unroll
  for (int ni = 0; ni < 4; ni++) {
    const int col = cbase + ni * 16;
    const float bv = bias[col];
#pragma unroll
    for (int mi = 0; mi < 4; mi++) {
#pragma unroll
      for (int r = 0; r < 4; r++) {
        const int row = rbase + mi * 16 + r;
        float v = acc[mi][ni][r] + bv;
        if (MODE == 0) {
          ((unsigned short*)outp)[(size_t)row * Nn + col] = bf16u(v);
        } else {
          float g = 0.5f * v * (1.0f + erff(v * 0.70710678118654752f));
          ((unsigned short*)outp)[(size_t)row * Nn + col] = bf16u(g);
        }
      }
    }
  }
}

// ---- GEMM 64x128, double-buffered LDS, optional split-K via blockIdx.z ----
// MODE 1: out fp32 = acc + bias + pos[(row%196)*Nn + col]   (patch embed, z=1)
// MODE 2: out fp32 atomicAdd(acc [+ bias if z==0])          (residual, z=2)
template <int MODE>
__global__ __launch_bounds__(256, 4) void gemm64_bt(
    const unsigned short* __restrict__ A, const unsigned short* __restrict__ W,
    const float* __restrict__ bias, const float* __restrict__ aux,
    float* __restrict__ outp, int K, int Nn) {
  __shared__ unsigned short As[2][64 * 32];
  __shared__ unsigned short Bs[2][128 * 32];
  const int tid = threadIdx.x;
  const int wave = tid >> 6, lane = tid & 63;
  const int tm = blockIdx.y * 64, tn = blockIdx.x * 128;
  const int kz = blockIdx.z;
  const int kper = K / gridDim.z;          // split-K slice (multiple of 32)
  const int kbase = kz * kper;
  const int wm = (wave >> 1) * 32, wn = (wave & 1) * 64;
  const int lr = lane & 15, kq = lane >> 4;
  const int sw = (lr >> 1) & 3;
  const int koff = (kq ^ sw) * 8;
  const int ra = tid >> 2;
  const int kca = ((tid & 3) ^ ((ra >> 1) & 3)) * 8;
  const int c0 = tid, c1 = tid + 256;
  const int r0 = c0 >> 2, r1 = c1 >> 2;
  const int kc0 = ((c0 & 3) ^ ((r0 >> 1) & 3)) * 8;
  const int kc1 = ((c1 & 3) ^ ((r1 >> 1) & 3)) * 8;
  const size_t ga  = (size_t)(tm + ra) * K + kca + kbase;
  const size_t gb0 = (size_t)(tn + r0) * K + kc0 + kbase;
  const size_t gb1 = (size_t)(tn + r1) * K + kc1 + kbase;
  floatx4 acc[2][4] = {};
  auto stage = [&](int buf, int k0) {
    gl2lds16(A + ga + k0, &As[buf][tid * 8]);
    gl2lds16(W + gb0 + k0, &Bs[buf][c0 * 8]);
    gl2lds16(W + gb1 + k0, &Bs[buf][c1 * 8]);
  };
  const int nk = kper >> 5;
  stage(0, 0);
  for (int it = 0; it < nk; it++) {
    const int cur = it & 1;
    __syncthreads();
    if (it + 1 < nk) stage(cur ^ 1, (it + 1) << 5);
    bf16x8 af[2], bq[4];
#pragma unroll
    for (int mi = 0; mi < 2; mi++)
      af[mi] = *(const bf16x8*)&As[cur][(wm + mi * 16 + lr) * 32 + koff];
#pragma unroll
    for (int ni = 0; ni < 4; ni++)
      bq[ni] = *(const bf16x8*)&Bs[cur][(wn + ni * 16 + lr) * 32 + koff];
#pragma unroll
    for (int mi = 0; mi < 2; mi++)
#pragma unroll
      for (int ni = 0; ni < 4; ni++)
        acc[mi][ni] = mfma_bf16(af[mi], bq[ni], acc[mi][ni]);
  }
  const int rbase = tm + wm + (lane >> 4) * 4;
  const int cbase = tn + wn + lr;
#pragma unroll
  for (int ni = 0; ni < 4; ni++) {
    const int col = cbase + ni * 16;
    const float bv = (MODE == 1 || kz == 0) ? bias[col] : 0.0f;
#pragma unroll
    for (int mi = 0; mi < 2; mi++) {
#pragma unroll
      for (int r = 0; r < 4; r++) {
        const int row = rbase + mi * 16 + r;
        float v = acc[mi][ni][r] + bv;
        float* hp = outp + (size_t)row * Nn + col;
        if (MODE == 1) *hp = v + aux[(size_t)(row % NN) * Nn + col];
        else           atomicAdd(hp, v);
      }
    }
  }
}

// ---- fused scores+softmax: per (bh, 32-row Q tile) -> P bf16 (rows x 224) ----
__global__ __launch_bounds__(256) void attn_sm_k(const unsigned short* __restrict__ qkv,
                                                 unsigned short* __restrict__ P) {
  __shared__ float S[32][232];             // +8 pad
  const int tid = threadIdx.x;
  const int bh = blockIdx.x;
  const int b = bh / HH, hh = bh % HH;
  const int i0 = blockIdx.y * 32;
  const int wave = tid >> 6, lane = tid & 63;
  const int lr = lane & 15, k8 = (lane >> 4) * 8;
  // 2x14 grid of 16x16 S tiles, 7 per wave
  for (int t = wave; t < 28; t += 4) {
    const int til = (t / 14) * 16, tj = (t % 14) * 16;
    const int iq = min(i0 + til + lr, NN - 1), jk = min(tj + lr, NN - 1);
    const unsigned short* qb = qkv + (size_t)(b * NN + iq) * 2304 + hh * 64 + k8;
    const unsigned short* kb = qkv + (size_t)(b * NN + jk) * 2304 + 768 + hh * 64 + k8;
    floatx4 acc = {0.f, 0.f, 0.f, 0.f};
    acc = mfma_bf16(*(const bf16x8*)qb, *(const bf16x8*)kb, acc);
    acc = mfma_bf16(*(const bf16x8*)(qb + 32), *(const bf16x8*)(kb + 32), acc);
#pragma unroll
    for (int r = 0; r < 4; r++)
      S[til + (lane >> 4) * 4 + r][tj + lr] = acc[r] * 0.125f;
  }
  __syncthreads();
  // softmax: 8 threads per row (row = tid>>3), cols strided by 8
  const int row = tid >> 3, sub = tid & 7;
  float v[28];
  float m = -1e30f;
#pragma unroll
  for (int t = 0; t < 28; t++) {
    const int c = sub + t * 8;
    v[t] = (c < NN) ? S[row][c] : -1e30f;
    m = fmaxf(m, v[t]);
  }
  m = fmaxf(m, __shfl_xor(m, 1));
  m = fmaxf(m, __shfl_xor(m, 2));
  m = fmaxf(m, __shfl_xor(m, 4));
  float s = 0.f;
#pragma unroll
  for (int t = 0; t < 28; t++) {
    v[t] = (sub + t * 8 < NN) ? __expf(v[t] - m) : 0.f;
    s += v[t];
  }
  s += __shfl_xor(s, 1);
  s += __shfl_xor(s, 2);
  s += __shfl_xor(s, 4);
  const float inv = 1.0f / s;
  const int gi = i0 + row;
  if (gi < NN) {
    unsigned short* prow = P + ((size_t)bh * NN + gi) * 224;
#pragma unroll
    for (int t = 0; t < 28; t++) prow[sub + t * 8] = bf16u(v[t] * inv);
  }
}

// ---- V transpose: Vt[bh][d][jp] = V[b,j,h,d], zero for j>=196 ----
__global__ __launch_bounds__(256) void vt_k(const unsigned short* __restrict__ qkv,
                                            unsigned short* __restrict__ Vt) {
  int idx = blockIdx.x * 256 + threadIdx.x;     // 384*64*224 exactly
  int j = idx % 224;
  int rest = idx / 224;
  int d = rest % 64, bh = rest / 64;
  int b = bh / HH, hh = bh % HH;
  unsigned short val = 0;
  if (j < NN) val = qkv[(size_t)(b * NN + j) * 2304 + 1536 + hh * 64 + d];
  Vt[idx] = val;
}

// ---- PV: o[b,i, h*64+d] = sum_j P[bh][i][j] * Vt[bh][d][j] ----
__global__ __launch_bounds__(256) void pv_k(const unsigned short* __restrict__ P,
                                            const unsigned short* __restrict__ Vt,
                                            unsigned short* __restrict__ o) {
  const int bh = blockIdx.x;
  const int b = bh / HH, hh = bh % HH;
  const int t = blockIdx.y * 4 + (threadIdx.x >> 6);
  const int it = t >> 2, dt = t & 3;
  const int lane = threadIdx.x & 63, lr = lane & 15, k8 = (lane >> 4) * 8;
  const int ip = min(it * 16 + lr, NN - 1);
  const unsigned short* pb = P + ((size_t)bh * NN + ip) * 224 + k8;
  const unsigned short* vb = Vt + ((size_t)bh * 64 + dt * 16 + lr) * 224 + k8;
  floatx4 acc = {0.f, 0.f, 0.f, 0.f};
#pragma unroll
  for (int k0 = 0; k0 < 224; k0 += 32)
    acc = mfma_bf16(*(const bf16x8*)(pb + k0), *(const bf16x8*)(vb + k0), acc);
#pragma unroll
  for (int r = 0; r < 4; r++) {
    int i = it * 16 + (lane >> 4) * 4 + r;
    if (i < NN)
      o[(size_t)(b * NN + i) * DD + hh * 64 + dt * 16 + lr] = bf16u(acc[r]);
  }
}

extern "C" void kernel_launch(void* const* d_in, const int* in_sizes, int n_in,
                              void* d_out, int out_size, void* d_ws, size_t ws_size,
                              hipStream_t stream) {
  const float* x       = (const float*)d_in[0];
  const float* patchw  = (const float*)d_in[1];
  const float* patchb  = (const float*)d_in[2];
  const float* pos     = (const float*)d_in[3];
  const float* ln1w    = (const float*)d_in[4];
  const float* ln1b    = (const float*)d_in[5];
  const float* qkvw    = (const float*)d_in[6];
  const float* qkvb    = (const float*)d_in[7];
  const float* projw   = (const float*)d_in[8];
  const float* projb   = (const float*)d_in[9];
  const float* ln2w    = (const float*)d_in[10];
  const float* ln2b    = (const float*)d_in[11];
  const float* fc1w    = (const float*)d_in[12];
  const float* fc1b    = (const float*)d_in[13];
  const float* fc2w    = (const float*)d_in[14];
  const float* fc2b    = (const float*)d_in[15];
  const float* lnfw    = (const float*)d_in[16];
  const float* lnfb    = (const float*)d_in[17];

  char* base = (char*)d_ws;
  size_t off = 0;
  auto alloc = [&](size_t bytes) {
    void* p = base + off;
    off = (off + bytes + 255) & ~(size_t)255;
    return p;
  };
  unsigned short* Wq  = (unsigned short*)alloc((size_t)LL * 2304 * 768 * 2);
  unsigned short* Wp  = (unsigned short*)alloc((size_t)LL * 768 * 768 * 2);
  unsigned short* W1  = (unsigned short*)alloc((size_t)LL * 3072 * 768 * 2);
  unsigned short* W2  = (unsigned short*)alloc((size_t)LL * 768 * 3072 * 2);
  unsigned short* Wpe = (unsigned short*)alloc((size_t)768 * 768 * 2);
  float*          h   = (float*)alloc((size_t)MM * DD * 4);
  unsigned short* y   = (unsigned short*)alloc((size_t)MM * DD * 2);
  unsigned short* qkv = (unsigned short*)alloc((size_t)MM * 2304 * 2);
  unsigned short* g   = (unsigned short*)alloc((size_t)MM * FFF * 2);  // fc1 out
  unsigned short* P   = (unsigned short*)alloc((size_t)BHH * NN * 224 * 2);
  unsigned short* Vt  = (unsigned short*)alloc((size_t)BHH * 64 * 224 * 2);
  unsigned short* o   = (unsigned short*)alloc((size_t)MM * DD * 2);
  if (off > ws_size) return;  // workspace too small: fail loudly (wrong output)

  unsigned short* Aim = qkv;  // im2col buffer aliases qkv (dead by layer 0)

  auto cvt = [&](const float* src, unsigned short* dst, size_t n) {
    int n4 = (int)(n / 4);
    cvt4_k<<<dim3((n4 + 255) / 256), dim3(256), 0, stream>>>(
        (const float4*)src, (ushort4*)dst, n4);
  };
  cvt(qkvw, Wq, (size_t)LL * 2304 * 768);
  cvt(projw, Wp, (size_t)LL * 768 * 768);
  cvt(fc1w, W1, (size_t)LL * 3072 * 768);
  cvt(fc2w, W2, (size_t)LL * 768 * 3072);
  cvt(patchw, Wpe, (size_t)768 * 768);

  im2col_k<<<dim3(MM * DD / 256), dim3(256), 0, stream>>>(x, Aim);
  // patch embed GEMM: h = Aim @ Wpe^T + patch_b + pos
  gemm64_bt<1><<<dim3(6, 98), dim3(256), 0, stream>>>(Aim, Wpe, patchb, pos, h, 768, 768);

  for (int l = 0; l < LL; l++) {
    ln_k<0><<<dim3(MM), dim3(256), 0, stream>>>(h, ln1w + l * 768, ln1b + l * 768, y);
    gemm_bt<0><<<dim3(18, 49), dim3(256), 0, stream>>>(
        y, Wq + (size_t)l * 2304 * 768, qkvb + l * 2304, qkv, 768, 2304);
    attn_sm_k<<<dim3(BHH, 7), dim3(256), 0, stream>>>(qkv, P);
    vt_k<<<dim3(BHH * 64 * 224 / 256), dim3(256), 0, stream>>>(qkv, Vt);
    pv_k<<<dim3(BHH, 13), dim3(256), 0, stream>>>(P, Vt, o);
    // proj: split-K=2, atomic accumulate into h
    gemm64_bt<2><<<dim3(6, 98, 2), dim3(256), 0, stream>>>(
        o, Wp + (size_t)l * 768 * 768, projb + l * 768, nullptr, h, 768, 768);
    ln_k<0><<<dim3(MM), dim3(256), 0, stream>>>(h, ln2w + l * 768, ln2b + l * 768, y);
    gemm_bt<3><<<dim3(24, 49), dim3(256), 0, stream>>>(
        y, W1 + (size_t)l * 3072 * 768, fc1b + l * 3072, g, 768, 3072);
    // fc2: split-K=2, atomic accumulate into h
    gemm64_bt<2><<<dim3(6, 98, 2), dim3(256), 0, stream>>>(
        g, W2 + (size_t)l * 768 * 3072, fc2b + l * 768, nullptr, h, 3072, 768);
  }
  ln_k<1><<<dim3(MM), dim3(256), 0, stream>>>(h, lnfw, lnfb, d_out);
}

// Round 3
// 3788.165 us; speedup vs baseline: 1.1163x; 1.1163x over previous
//
#include <hip/hip_runtime.h>
#include <hip/hip_bf16.h>
#include <math.h>

// ---- constants ----
#define BB    32
#define DD    768
#define LL    12
#define HH    12
#define NN    196
#define DHH   64
#define FFF   3072
#define MM    (BB * NN)      // 6272 tokens
#define BHH   (BB * HH)      // 384

typedef float  floatx4 __attribute__((ext_vector_type(4)));
typedef __bf16 bf16x8  __attribute__((ext_vector_type(8)));

#define DEV __device__ __forceinline__

DEV unsigned short bf16u(float v) {
  __hip_bfloat16 h = __float2bfloat16(v);
  return __builtin_bit_cast(unsigned short, h);
}

DEV floatx4 mfma_bf16(bf16x8 a, bf16x8 b, floatx4 c) {
  return __builtin_amdgcn_mfma_f32_16x16x32_bf16(a, b, c, 0, 0, 0);
}

DEV void gl2lds16(const void* g, void* l) {
  __builtin_amdgcn_global_load_lds(
      (const __attribute__((address_space(1))) void*)g,
      (__attribute__((address_space(3))) void*)l, 16, 0, 0);
}

// ---- fp32 -> bf16 conversion (vectorized) ----
__global__ __launch_bounds__(256) void cvt4_k(const float4* __restrict__ in,
                                              ushort4* __restrict__ out, int n4) {
  int i = blockIdx.x * 256 + threadIdx.x;
  if (i < n4) {
    float4 v = in[i];
    ushort4 o;
    o.x = bf16u(v.x); o.y = bf16u(v.y); o.z = bf16u(v.z); o.w = bf16u(v.w);
    out[i] = o;
  }
}

// ---- im2col for patch embed: x (32,3,224,224) -> A (6272, 768) bf16 ----
__global__ __launch_bounds__(256) void im2col_k(const float* __restrict__ x,
                                                unsigned short* __restrict__ A) {
  int idx = blockIdx.x * 256 + threadIdx.x;      // grid covers 6272*768 exactly
  int col = idx % DD;
  int token = idx / DD;
  int b = token / NN, p = token % NN;
  int pr = p / 14, pc = p % 14;
  int c = col >> 8, rm = col & 255, i = rm >> 4, j = rm & 15;
  float v = x[(((size_t)b * 3 + c) * 224 + pr * 16 + i) * 224 + pc * 16 + j];
  A[idx] = bf16u(v);
}

// ---- LayerNorm: h fp32 (M,768) -> y bf16 ----
__global__ __launch_bounds__(256) void ln_k(const float* __restrict__ x,
                                            const float* __restrict__ w,
                                            const float* __restrict__ bb,
                                            unsigned short* __restrict__ outp) {
  const int token = blockIdx.x, tid = threadIdx.x;
  const float* xr = x + (size_t)token * DD;
  float v0 = xr[tid], v1 = xr[tid + 256], v2 = xr[tid + 512];
  float s = v0 + v1 + v2;
  float ss = v0 * v0 + v1 * v1 + v2 * v2;
#pragma unroll
  for (int off = 32; off; off >>= 1) {
    s += __shfl_down(s, off);
    ss += __shfl_down(ss, off);
  }
  __shared__ float rs[4], rq[4];
  if ((tid & 63) == 0) { rs[tid >> 6] = s; rq[tid >> 6] = ss; }
  __syncthreads();
  float tot = rs[0] + rs[1] + rs[2] + rs[3];
  float tq  = rq[0] + rq[1] + rq[2] + rq[3];
  const float mean = tot * (1.0f / 768.0f);
  const float var  = tq * (1.0f / 768.0f) - mean * mean;
  const float rstd = rsqrtf(var + 1e-5f);
#pragma unroll
  for (int t = 0; t < 3; t++) {
    int col = tid + t * 256;
    float xv = (t == 0) ? v0 : (t == 1 ? v1 : v2);
    float yv = (xv - mean) * rstd * w[col] + bb[col];
    outp[(size_t)token * DD + col] = bf16u(yv);
  }
}

// ---- fused residual-reduce + LayerNorm:
// t = h + p0 + p1;  (FINAL==0) h = t, y = bf16(LN(t));  (FINAL==1) out = fp32 LN(t)
template <int FINAL>
__global__ __launch_bounds__(256) void ln_fuse_k(float* __restrict__ h,
    const float* __restrict__ p0, const float* __restrict__ p1,
    const float* __restrict__ w, const float* __restrict__ bb,
    void* __restrict__ outp) {
  const int token = blockIdx.x, tid = threadIdx.x;
  const size_t base = (size_t)token * DD;
  float v[3];
#pragma unroll
  for (int t = 0; t < 3; t++) {
    const int col = tid + t * 256;
    v[t] = h[base + col] + p0[base + col] + p1[base + col];
    if (!FINAL) h[base + col] = v[t];
  }
  float s = v[0] + v[1] + v[2];
  float ss = v[0] * v[0] + v[1] * v[1] + v[2] * v[2];
#pragma unroll
  for (int off = 32; off; off >>= 1) {
    s += __shfl_down(s, off);
    ss += __shfl_down(ss, off);
  }
  __shared__ float rs[4], rq[4];
  if ((tid & 63) == 0) { rs[tid >> 6] = s; rq[tid >> 6] = ss; }
  __syncthreads();
  float tot = rs[0] + rs[1] + rs[2] + rs[3];
  float tq  = rq[0] + rq[1] + rq[2] + rq[3];
  const float mean = tot * (1.0f / 768.0f);
  const float var  = tq * (1.0f / 768.0f) - mean * mean;
  const float rstd = rsqrtf(var + 1e-5f);
#pragma unroll
  for (int t = 0; t < 3; t++) {
    const int col = tid + t * 256;
    float yv = (v[t] - mean) * rstd * w[col] + bb[col];
    if (FINAL) ((float*)outp)[base + col] = yv;
    else       ((unsigned short*)outp)[base + col] = bf16u(yv);
  }
}

// LDS k-chunk XOR swizzle (verified: conflicts -> 0): LDS slot (row,s)
// holds global k-chunk s ^ ((row>>1)&3); staging permutes the GLOBAL source,
// reads apply the same XOR.

// ---- GEMM 128x128, double-buffered LDS ----
// MODE 0: out bf16 = acc + bias
// MODE 3: out bf16 = gelu(acc + bias)
template <int MODE>
__global__ __launch_bounds__(256, 4) void gemm_bt(
    const unsigned short* __restrict__ A, const unsigned short* __restrict__ W,
    const float* __restrict__ bias, void* __restrict__ outp, int K, int Nn) {
  __shared__ unsigned short As[2][128 * 32];
  __shared__ unsigned short Bs[2][128 * 32];
  const int tid = threadIdx.x;
  const int wave = tid >> 6, lane = tid & 63;
  const int tm = blockIdx.y * 128, tn = blockIdx.x * 128;
  const int wm = (wave >> 1) * 64, wn = (wave & 1) * 64;
  const int lr = lane & 15, kq = lane >> 4;
  const int sw = (lr >> 1) & 3;
  const int koff = (kq ^ sw) * 8;
  const int c0 = tid, c1 = tid + 256;
  const int r0 = c0 >> 2, r1 = c1 >> 2;
  const int kc0 = ((c0 & 3) ^ ((r0 >> 1) & 3)) * 8;
  const int kc1 = ((c1 & 3) ^ ((r1 >> 1) & 3)) * 8;
  const size_t ga0 = (size_t)(tm + r0) * K + kc0;
  const size_t ga1 = (size_t)(tm + r1) * K + kc1;
  const size_t gb0 = (size_t)(tn + r0) * K + kc0;
  const size_t gb1 = (size_t)(tn + r1) * K + kc1;
  floatx4 acc[4][4] = {};
  auto stage = [&](int buf, int k0) {
    gl2lds16(A + ga0 + k0, &As[buf][c0 * 8]);
    gl2lds16(A + ga1 + k0, &As[buf][c1 * 8]);
    gl2lds16(W + gb0 + k0, &Bs[buf][c0 * 8]);
    gl2lds16(W + gb1 + k0, &Bs[buf][c1 * 8]);
  };
  const int nk = K >> 5;
  stage(0, 0);
  for (int it = 0; it < nk; it++) {
    const int cur = it & 1;
    __syncthreads();                       // drains stage(cur) (issued last iter)
    if (it + 1 < nk) stage(cur ^ 1, (it + 1) << 5);
    bf16x8 af[4], bq[4];
#pragma unroll
    for (int mi = 0; mi < 4; mi++)
      af[mi] = *(const bf16x8*)&As[cur][(wm + mi * 16 + lr) * 32 + koff];
#pragma unroll
    for (int ni = 0; ni < 4; ni++)
      bq[ni] = *(const bf16x8*)&Bs[cur][(wn + ni * 16 + lr) * 32 + koff];
#pragma unroll
    for (int mi = 0; mi < 4; mi++)
#pragma unroll
      for (int ni = 0; ni < 4; ni++)
        acc[mi][ni] = mfma_bf16(af[mi], bq[ni], acc[mi][ni]);
  }
  const int rbase = tm + wm + (lane >> 4) * 4;
  const int cbase = tn + wn + lr;
#pragma unroll
  for (int ni = 0; ni < 4; ni++) {
    const int col = cbase + ni * 16;
    const float bv = bias[col];
#pragma unroll
    for (int mi = 0; mi < 4; mi++) {
#pragma unroll
      for (int r = 0; r < 4; r++) {
        const int row = rbase + mi * 16 + r;
        float v = acc[mi][ni][r] + bv;
        if (MODE == 0) {
          ((unsigned short*)outp)[(size_t)row * Nn + col] = bf16u(v);
        } else {
          float g = 0.5f * v * (1.0f + erff(v * 0.70710678118654752f));
          ((unsigned short*)outp)[(size_t)row * Nn + col] = bf16u(g);
        }
      }
    }
  }
}

// ---- GEMM 128x128, split-K=2 via blockIdx.z, fp32 partial outputs ----
// z=0 -> p0 (with bias), z=1 -> p1 (no bias). Reduce happens in ln_fuse_k.
__global__ __launch_bounds__(256, 4) void gemm_sk(
    const unsigned short* __restrict__ A, const unsigned short* __restrict__ W,
    const float* __restrict__ bias, float* __restrict__ p0,
    float* __restrict__ p1, int K, int Nn) {
  __shared__ unsigned short As[2][128 * 32];
  __shared__ unsigned short Bs[2][128 * 32];
  const int tid = threadIdx.x;
  const int wave = tid >> 6, lane = tid & 63;
  const int tm = blockIdx.y * 128, tn = blockIdx.x * 128;
  const int kz = blockIdx.z;
  const int kper = K >> 1;
  const int kbase = kz * kper;
  const int wm = (wave >> 1) * 64, wn = (wave & 1) * 64;
  const int lr = lane & 15, kq = lane >> 4;
  const int sw = (lr >> 1) & 3;
  const int koff = (kq ^ sw) * 8;
  const int c0 = tid, c1 = tid + 256;
  const int r0 = c0 >> 2, r1 = c1 >> 2;
  const int kc0 = ((c0 & 3) ^ ((r0 >> 1) & 3)) * 8;
  const int kc1 = ((c1 & 3) ^ ((r1 >> 1) & 3)) * 8;
  const size_t ga0 = (size_t)(tm + r0) * K + kc0 + kbase;
  const size_t ga1 = (size_t)(tm + r1) * K + kc1 + kbase;
  const size_t gb0 = (size_t)(tn + r0) * K + kc0 + kbase;
  const size_t gb1 = (size_t)(tn + r1) * K + kc1 + kbase;
  floatx4 acc[4][4] = {};
  auto stage = [&](int buf, int k0) {
    gl2lds16(A + ga0 + k0, &As[buf][c0 * 8]);
    gl2lds16(A + ga1 + k0, &As[buf][c1 * 8]);
    gl2lds16(W + gb0 + k0, &Bs[buf][c0 * 8]);
    gl2lds16(W + gb1 + k0, &Bs[buf][c1 * 8]);
  };
  const int nk = kper >> 5;
  stage(0, 0);
  for (int it = 0; it < nk; it++) {
    const int cur = it & 1;
    __syncthreads();
    if (it + 1 < nk) stage(cur ^ 1, (it + 1) << 5);
    bf16x8 af[4], bq[4];
#pragma unroll
    for (int mi = 0; mi < 4; mi++)
      af[mi] = *(const bf16x8*)&As[cur][(wm + mi * 16 + lr) * 32 + koff];
#pragma unroll
    for (int ni = 0; ni < 4; ni++)
      bq[ni] = *(const bf16x8*)&Bs[cur][(wn + ni * 16 + lr) * 32 + koff];
#pragma unroll
    for (int mi = 0; mi < 4; mi++)
#pragma unroll
      for (int ni = 0; ni < 4; ni++)
        acc[mi][ni] = mfma_bf16(af[mi], bq[ni], acc[mi][ni]);
  }
  float* __restrict__ po = kz ? p1 : p0;
  const int rbase = tm + wm + (lane >> 4) * 4;
  const int cbase = tn + wn + lr;
#pragma unroll
  for (int ni = 0; ni < 4; ni++) {
    const int col = cbase + ni * 16;
    const float bv = kz ? 0.0f : bias[col];
#pragma unroll
    for (int mi = 0; mi < 4; mi++) {
#pragma unroll
      for (int r = 0; r < 4; r++) {
        const int row = rbase + mi * 16 + r;
        po[(size_t)row * Nn + col] = acc[mi][ni][r] + bv;
      }
    }
  }
}

// ---- GEMM 64x128, double-buffered LDS (patch embed) ----
// MODE 1: out fp32 = acc + bias + pos[(row%196)*Nn + col]
template <int MODE>
__global__ __launch_bounds__(256, 4) void gemm64_bt(
    const unsigned short* __restrict__ A, const unsigned short* __restrict__ W,
    const float* __restrict__ bias, const float* __restrict__ aux,
    float* __restrict__ outp, int K, int Nn) {
  __shared__ unsigned short As[2][64 * 32];
  __shared__ unsigned short Bs[2][128 * 32];
  const int tid = threadIdx.x;
  const int wave = tid >> 6, lane = tid & 63;
  const int tm = blockIdx.y * 64, tn = blockIdx.x * 128;
  const int wm = (wave >> 1) * 32, wn = (wave & 1) * 64;
  const int lr = lane & 15, kq = lane >> 4;
  const int sw = (lr >> 1) & 3;
  const int koff = (kq ^ sw) * 8;
  const int ra = tid >> 2;
  const int kca = ((tid & 3) ^ ((ra >> 1) & 3)) * 8;
  const int c0 = tid, c1 = tid + 256;
  const int r0 = c0 >> 2, r1 = c1 >> 2;
  const int kc0 = ((c0 & 3) ^ ((r0 >> 1) & 3)) * 8;
  const int kc1 = ((c1 & 3) ^ ((r1 >> 1) & 3)) * 8;
  const size_t ga  = (size_t)(tm + ra) * K + kca;
  const size_t gb0 = (size_t)(tn + r0) * K + kc0;
  const size_t gb1 = (size_t)(tn + r1) * K + kc1;
  floatx4 acc[2][4] = {};
  auto stage = [&](int buf, int k0) {
    gl2lds16(A + ga + k0, &As[buf][tid * 8]);
    gl2lds16(W + gb0 + k0, &Bs[buf][c0 * 8]);
    gl2lds16(W + gb1 + k0, &Bs[buf][c1 * 8]);
  };
  const int nk = K >> 5;
  stage(0, 0);
  for (int it = 0; it < nk; it++) {
    const int cur = it & 1;
    __syncthreads();
    if (it + 1 < nk) stage(cur ^ 1, (it + 1) << 5);
    bf16x8 af[2], bq[4];
#pragma unroll
    for (int mi = 0; mi < 2; mi++)
      af[mi] = *(const bf16x8*)&As[cur][(wm + mi * 16 + lr) * 32 + koff];
#pragma unroll
    for (int ni = 0; ni < 4; ni++)
      bq[ni] = *(const bf16x8*)&Bs[cur][(wn + ni * 16 + lr) * 32 + koff];
#pragma unroll
    for (int mi = 0; mi < 2; mi++)
#pragma unroll
      for (int ni = 0; ni < 4; ni++)
        acc[mi][ni] = mfma_bf16(af[mi], bq[ni], acc[mi][ni]);
  }
  const int rbase = tm + wm + (lane >> 4) * 4;
  const int cbase = tn + wn + lr;
#pragma unroll
  for (int ni = 0; ni < 4; ni++) {
    const int col = cbase + ni * 16;
    const float bv = bias[col];
#pragma unroll
    for (int mi = 0; mi < 2; mi++) {
#pragma unroll
      for (int r = 0; r < 4; r++) {
        const int row = rbase + mi * 16 + r;
        float v = acc[mi][ni][r] + bv;
        float* hp = outp + (size_t)row * Nn + col;
        if (MODE == 1) *hp = v + aux[(size_t)(row % NN) * Nn + col];
        else           *hp = *hp + v;
      }
    }
  }
}

// ---- fused scores+softmax: per (bh, 32-row Q tile) -> P bf16 (rows x 224) ----
__global__ __launch_bounds__(256) void attn_sm_k(const unsigned short* __restrict__ qkv,
                                                 unsigned short* __restrict__ P) {
  __shared__ float S[32][232];             // +8 pad
  const int tid = threadIdx.x;
  const int bh = blockIdx.x;
  const int b = bh / HH, hh = bh % HH;
  const int i0 = blockIdx.y * 32;
  const int wave = tid >> 6, lane = tid & 63;
  const int lr = lane & 15, k8 = (lane >> 4) * 8;
  // 2x14 grid of 16x16 S tiles, 7 per wave
  for (int t = wave; t < 28; t += 4) {
    const int til = (t / 14) * 16, tj = (t % 14) * 16;
    const int iq = min(i0 + til + lr, NN - 1), jk = min(tj + lr, NN - 1);
    const unsigned short* qb = qkv + (size_t)(b * NN + iq) * 2304 + hh * 64 + k8;
    const unsigned short* kb = qkv + (size_t)(b * NN + jk) * 2304 + 768 + hh * 64 + k8;
    floatx4 acc = {0.f, 0.f, 0.f, 0.f};
    acc = mfma_bf16(*(const bf16x8*)qb, *(const bf16x8*)kb, acc);
    acc = mfma_bf16(*(const bf16x8*)(qb + 32), *(const bf16x8*)(kb + 32), acc);
#pragma unroll
    for (int r = 0; r < 4; r++)
      S[til + (lane >> 4) * 4 + r][tj + lr] = acc[r] * 0.125f;
  }
  __syncthreads();
  // softmax: 8 threads per row (row = tid>>3), cols strided by 8
  const int row = tid >> 3, sub = tid & 7;
  float v[28];
  float m = -1e30f;
#pragma unroll
  for (int t = 0; t < 28; t++) {
    const int c = sub + t * 8;
    v[t] = (c < NN) ? S[row][c] : -1e30f;
    m = fmaxf(m, v[t]);
  }
  m = fmaxf(m, __shfl_xor(m, 1));
  m = fmaxf(m, __shfl_xor(m, 2));
  m = fmaxf(m, __shfl_xor(m, 4));
  float s = 0.f;
#pragma unroll
  for (int t = 0; t < 28; t++) {
    v[t] = (sub + t * 8 < NN) ? __expf(v[t] - m) : 0.f;
    s += v[t];
  }
  s += __shfl_xor(s, 1);
  s += __shfl_xor(s, 2);
  s += __shfl_xor(s, 4);
  const float inv = 1.0f / s;
  const int gi = i0 + row;
  if (gi < NN) {
    unsigned short* prow = P + ((size_t)bh * NN + gi) * 224;
#pragma unroll
    for (int t = 0; t < 28; t++) prow[sub + t * 8] = bf16u(v[t] * inv);
  }
}

// ---- V transpose: Vt[bh][d][jp] = V[b,j,h,d], zero for j>=196 ----
__global__ __launch_bounds__(256) void vt_k(const unsigned short* __restrict__ qkv,
                                            unsigned short* __restrict__ Vt) {
  int idx = blockIdx.x * 256 + threadIdx.x;     // 384*64*224 exactly
  int j = idx % 224;
  int rest = idx / 224;
  int d = rest % 64, bh = rest / 64;
  int b = bh / HH, hh = bh % HH;
  unsigned short val = 0;
  if (j < NN) val = qkv[(size_t)(b * NN + j) * 2304 + 1536 + hh * 64 + d];
  Vt[idx] = val;
}

// ---- PV: o[b,i, h*64+d] = sum_j P[bh][i][j] * Vt[bh][d][j] ----
__global__ __launch_bounds__(256) void pv_k(const unsigned short* __restrict__ P,
                                            const unsigned short* __restrict__ Vt,
                                            unsigned short* __restrict__ o) {
  const int bh = blockIdx.x;
  const int b = bh / HH, hh = bh % HH;
  const int t = blockIdx.y * 4 + (threadIdx.x >> 6);
  const int it = t >> 2, dt = t & 3;
  const int lane = threadIdx.x & 63, lr = lane & 15, k8 = (lane >> 4) * 8;
  const int ip = min(it * 16 + lr, NN - 1);
  const unsigned short* pb = P + ((size_t)bh * NN + ip) * 224 + k8;
  const unsigned short* vb = Vt + ((size_t)bh * 64 + dt * 16 + lr) * 224 + k8;
  floatx4 acc = {0.f, 0.f, 0.f, 0.f};
#pragma unroll
  for (int k0 = 0; k0 < 224; k0 += 32)
    acc = mfma_bf16(*(const bf16x8*)(pb + k0), *(const bf16x8*)(vb + k0), acc);
#pragma unroll
  for (int r = 0; r < 4; r++) {
    int i = it * 16 + (lane >> 4) * 4 + r;
    if (i < NN)
      o[(size_t)(b * NN + i) * DD + hh * 64 + dt * 16 + lr] = bf16u(acc[r]);
  }
}

extern "C" void kernel_launch(void* const* d_in, const int* in_sizes, int n_in,
                              void* d_out, int out_size, void* d_ws, size_t ws_size,
                              hipStream_t stream) {
  const float* x       = (const float*)d_in[0];
  const float* patchw  = (const float*)d_in[1];
  const float* patchb  = (const float*)d_in[2];
  const float* pos     = (const float*)d_in[3];
  const float* ln1w    = (const float*)d_in[4];
  const float* ln1b    = (const float*)d_in[5];
  const float* qkvw    = (const float*)d_in[6];
  const float* qkvb    = (const float*)d_in[7];
  const float* projw   = (const float*)d_in[8];
  const float* projb   = (const float*)d_in[9];
  const float* ln2w    = (const float*)d_in[10];
  const float* ln2b    = (const float*)d_in[11];
  const float* fc1w    = (const float*)d_in[12];
  const float* fc1b    = (const float*)d_in[13];
  const float* fc2w    = (const float*)d_in[14];
  const float* fc2b    = (const float*)d_in[15];
  const float* lnfw    = (const float*)d_in[16];
  const float* lnfb    = (const float*)d_in[17];

  char* base = (char*)d_ws;
  size_t off = 0;
  auto alloc = [&](size_t bytes) {
    void* p = base + off;
    off = (off + bytes + 255) & ~(size_t)255;
    return p;
  };
  unsigned short* Wq  = (unsigned short*)alloc((size_t)LL * 2304 * 768 * 2);
  unsigned short* Wp  = (unsigned short*)alloc((size_t)LL * 768 * 768 * 2);
  unsigned short* W1  = (unsigned short*)alloc((size_t)LL * 3072 * 768 * 2);
  unsigned short* W2  = (unsigned short*)alloc((size_t)LL * 768 * 3072 * 2);
  unsigned short* Wpe = (unsigned short*)alloc((size_t)768 * 768 * 2);
  float*          h   = (float*)alloc((size_t)MM * DD * 4);
  unsigned short* y   = (unsigned short*)alloc((size_t)MM * DD * 2);
  unsigned short* qkv = (unsigned short*)alloc((size_t)MM * 2304 * 2);   // 28.9 MB
  unsigned short* g   = (unsigned short*)alloc((size_t)MM * FFF * 2);    // fc1 out
  unsigned short* P   = (unsigned short*)alloc((size_t)BHH * NN * 224 * 2); // 33.7 MB
  unsigned short* Vt  = (unsigned short*)alloc((size_t)BHH * 64 * 224 * 2);
  unsigned short* o   = (unsigned short*)alloc((size_t)MM * DD * 2);
  if (off > ws_size) return;  // workspace too small: fail loudly (wrong output)

  unsigned short* Aim = qkv;  // im2col buffer aliases qkv (dead by layer 0)
  // Split-K partial buffers (fp32, 19.27 MB each). Lifetimes: written by
  // gemm_sk (proj or fc2), read once by the immediately-following ln_fuse_k.
  // qkv is dead after vt_k; P is dead after pv_k — both regions free during
  // proj->ln2 and fc2->next-ln1 windows, and both hold >= MM*DD*4 bytes.
  float* pp0 = (float*)qkv;   // 19.27 <= 28.9 MB
  float* pp1 = (float*)P;     // 19.27 <= 33.7 MB

  auto cvt = [&](const float* src, unsigned short* dst, size_t n) {
    int n4 = (int)(n / 4);
    cvt4_k<<<dim3((n4 + 255) / 256), dim3(256), 0, stream>>>(
        (const float4*)src, (ushort4*)dst, n4);
  };
  cvt(qkvw, Wq, (size_t)LL * 2304 * 768);
  cvt(projw, Wp, (size_t)LL * 768 * 768);
  cvt(fc1w, W1, (size_t)LL * 3072 * 768);
  cvt(fc2w, W2, (size_t)LL * 768 * 3072);
  cvt(patchw, Wpe, (size_t)768 * 768);

  im2col_k<<<dim3(MM * DD / 256), dim3(256), 0, stream>>>(x, Aim);
  // patch embed GEMM: h = Aim @ Wpe^T + patch_b + pos
  gemm64_bt<1><<<dim3(6, 98), dim3(256), 0, stream>>>(Aim, Wpe, patchb, pos, h, 768, 768);

  // layer 0 ln1 (plain)
  ln_k<<<dim3(MM), dim3(256), 0, stream>>>(h, ln1w, ln1b, y);

  for (int l = 0; l < LL; l++) {
    gemm_bt<0><<<dim3(18, 49), dim3(256), 0, stream>>>(
        y, Wq + (size_t)l * 2304 * 768, qkvb + l * 2304, qkv, 768, 2304);
    attn_sm_k<<<dim3(BHH, 7), dim3(256), 0, stream>>>(qkv, P);
    vt_k<<<dim3(BHH * 64 * 224 / 256), dim3(256), 0, stream>>>(qkv, Vt);
    pv_k<<<dim3(BHH, 13), dim3(256), 0, stream>>>(P, Vt, o);
    // proj: 128x128 tile, split-K=2, fp32 partials (overwrite qkv/P regions)
    gemm_sk<<<dim3(6, 49, 2), dim3(256), 0, stream>>>(
        o, Wp + (size_t)l * 768 * 768, projb + l * 768, pp0, pp1, 768, 768);
    // h += pp0+pp1; y = ln2(h)
    ln_fuse_k<0><<<dim3(MM), dim3(256), 0, stream>>>(
        h, pp0, pp1, ln2w + l * 768, ln2b + l * 768, y);
    gemm_bt<3><<<dim3(24, 49), dim3(256), 0, stream>>>(
        y, W1 + (size_t)l * 3072 * 768, fc1b + l * 3072, g, 768, 3072);
    // fc2: 128x128 tile, split-K=2, fp32 partials
    gemm_sk<<<dim3(6, 49, 2), dim3(256), 0, stream>>>(
        g, W2 + (size_t)l * 768 * 3072, fc2b + l * 768, pp0, pp1, 3072, 768);
    if (l + 1 < LL) {
      // h += pp0+pp1; y = ln1_{l+1}(h)
      ln_fuse_k<0><<<dim3(MM), dim3(256), 0, stream>>>(
          h, pp0, pp1, ln1w + (l + 1) * 768, ln1b + (l + 1) * 768, y);
    } else {
      // final: out = lnf(h + pp0 + pp1), fp32
      ln_fuse_k<1><<<dim3(MM), dim3(256), 0, stream>>>(
          h, pp0, pp1, lnfw, lnfb, d_out);
    }
  }
}

// Round 4
// 3506.414 us; speedup vs baseline: 1.2060x; 1.0804x over previous
//
#include <hip/hip_runtime.h>
#include <hip/hip_bf16.h>
#include <math.h>

// ---- constants ----
#define BB    32
#define DD    768
#define LL    12
#define HH    12
#define NN    196
#define DHH   64
#define FFF   3072
#define MM    (BB * NN)      // 6272 tokens
#define BHH   (BB * HH)      // 384

typedef float  floatx4 __attribute__((ext_vector_type(4)));
typedef __bf16 bf16x8  __attribute__((ext_vector_type(8)));

#define DEV __device__ __forceinline__

DEV unsigned short bf16u(float v) {
  __hip_bfloat16 h = __float2bfloat16(v);
  return __builtin_bit_cast(unsigned short, h);
}

DEV floatx4 mfma_bf16(bf16x8 a, bf16x8 b, floatx4 c) {
  return __builtin_amdgcn_mfma_f32_16x16x32_bf16(a, b, c, 0, 0, 0);
}

DEV void gl2lds16(const void* g, void* l) {
  __builtin_amdgcn_global_load_lds(
      (const __attribute__((address_space(1))) void*)g,
      (__attribute__((address_space(3))) void*)l, 16, 0, 0);
}

// Fast erf (Abramowitz-Stegun 7.1.26, |err| <= 1.5e-7 — far below bf16 ulp).
// gelu(v) = 0.5 v (1 + erf(v/sqrt(2)))
DEV float gelu_f(float v) {
  float ax = fabsf(v) * 0.70710678118654752f;
  float t = 1.0f / (1.0f + 0.3275911f * ax);
  float poly = t * (0.254829592f +
              t * (-0.284496736f +
              t * (1.421413741f +
              t * (-1.453152027f +
              t * 1.061405429f))));
  float er = 1.0f - poly * __expf(-ax * ax);
  er = (v < 0.0f) ? -er : er;
  return 0.5f * v * (1.0f + er);
}

// Bijective XCD chunk transform (m204): orig%8 -> XCD; each XCD gets a
// contiguous range of linear tile ids (M-bands) -> L2 locality per XCD.
DEV int xcd_swz(int orig, int nwg) {
  int q = nwg >> 3, r = nwg & 7;
  int xcd = orig & 7, pos = orig >> 3;
  int base = (xcd < r) ? xcd * (q + 1) : r * (q + 1) + (xcd - r) * q;
  return base + pos;
}

// ---- fp32 -> bf16 conversion (vectorized) ----
__global__ __launch_bounds__(256) void cvt4_k(const float4* __restrict__ in,
                                              ushort4* __restrict__ out, int n4) {
  int i = blockIdx.x * 256 + threadIdx.x;
  if (i < n4) {
    float4 v = in[i];
    ushort4 o;
    o.x = bf16u(v.x); o.y = bf16u(v.y); o.z = bf16u(v.z); o.w = bf16u(v.w);
    out[i] = o;
  }
}

// ---- im2col for patch embed: x (32,3,224,224) -> A (6272, 768) bf16 ----
__global__ __launch_bounds__(256) void im2col_k(const float* __restrict__ x,
                                                unsigned short* __restrict__ A) {
  int idx = blockIdx.x * 256 + threadIdx.x;      // grid covers 6272*768 exactly
  int col = idx % DD;
  int token = idx / DD;
  int b = token / NN, p = token % NN;
  int pr = p / 14, pc = p % 14;
  int c = col >> 8, rm = col & 255, i = rm >> 4, j = rm & 15;
  float v = x[(((size_t)b * 3 + c) * 224 + pr * 16 + i) * 224 + pc * 16 + j];
  A[idx] = bf16u(v);
}

// ---- LayerNorm: h fp32 (M,768) -> y bf16 ----
__global__ __launch_bounds__(256) void ln_k(const float* __restrict__ x,
                                            const float* __restrict__ w,
                                            const float* __restrict__ bb,
                                            unsigned short* __restrict__ outp) {
  const int token = blockIdx.x, tid = threadIdx.x;
  const float* xr = x + (size_t)token * DD;
  float v0 = xr[tid], v1 = xr[tid + 256], v2 = xr[tid + 512];
  float s = v0 + v1 + v2;
  float ss = v0 * v0 + v1 * v1 + v2 * v2;
#pragma unroll
  for (int off = 32; off; off >>= 1) {
    s += __shfl_down(s, off);
    ss += __shfl_down(ss, off);
  }
  __shared__ float rs[4], rq[4];
  if ((tid & 63) == 0) { rs[tid >> 6] = s; rq[tid >> 6] = ss; }
  __syncthreads();
  float tot = rs[0] + rs[1] + rs[2] + rs[3];
  float tq  = rq[0] + rq[1] + rq[2] + rq[3];
  const float mean = tot * (1.0f / 768.0f);
  const float var  = tq * (1.0f / 768.0f) - mean * mean;
  const float rstd = rsqrtf(var + 1e-5f);
#pragma unroll
  for (int t = 0; t < 3; t++) {
    int col = tid + t * 256;
    float xv = (t == 0) ? v0 : (t == 1 ? v1 : v2);
    float yv = (xv - mean) * rstd * w[col] + bb[col];
    outp[(size_t)token * DD + col] = bf16u(yv);
  }
}

// ---- fused residual-reduce + LayerNorm:
// t = h + p0 + p1;  (FINAL==0) h = t, y = bf16(LN(t));  (FINAL==1) out = fp32 LN(t)
template <int FINAL>
__global__ __launch_bounds__(256) void ln_fuse_k(float* __restrict__ h,
    const float* __restrict__ p0, const float* __restrict__ p1,
    const float* __restrict__ w, const float* __restrict__ bb,
    void* __restrict__ outp) {
  const int token = blockIdx.x, tid = threadIdx.x;
  const size_t base = (size_t)token * DD;
  float v[3];
#pragma unroll
  for (int t = 0; t < 3; t++) {
    const int col = tid + t * 256;
    v[t] = h[base + col] + p0[base + col] + p1[base + col];
    if (!FINAL) h[base + col] = v[t];
  }
  float s = v[0] + v[1] + v[2];
  float ss = v[0] * v[0] + v[1] * v[1] + v[2] * v[2];
#pragma unroll
  for (int off = 32; off; off >>= 1) {
    s += __shfl_down(s, off);
    ss += __shfl_down(ss, off);
  }
  __shared__ float rs[4], rq[4];
  if ((tid & 63) == 0) { rs[tid >> 6] = s; rq[tid >> 6] = ss; }
  __syncthreads();
  float tot = rs[0] + rs[1] + rs[2] + rs[3];
  float tq  = rq[0] + rq[1] + rq[2] + rq[3];
  const float mean = tot * (1.0f / 768.0f);
  const float var  = tq * (1.0f / 768.0f) - mean * mean;
  const float rstd = rsqrtf(var + 1e-5f);
#pragma unroll
  for (int t = 0; t < 3; t++) {
    const int col = tid + t * 256;
    float yv = (v[t] - mean) * rstd * w[col] + bb[col];
    if (FINAL) ((float*)outp)[base + col] = yv;
    else       ((unsigned short*)outp)[base + col] = bf16u(yv);
  }
}

// LDS k-chunk XOR swizzle (verified: conflicts -> 0): LDS slot (row,s)
// holds global k-chunk s ^ ((row>>1)&3); staging permutes the GLOBAL source,
// reads apply the same XOR.

// ---- GEMM 128x128, double-buffered LDS ----
// MODE 0: out bf16 = acc + bias
// MODE 3: out bf16 = gelu(acc + bias)
// Epilogue: acc -> LDS (reuse staging buffers) -> coalesced 16B stores.
template <int MODE>
__global__ __launch_bounds__(256, 4) void gemm_bt(
    const unsigned short* __restrict__ A, const unsigned short* __restrict__ W,
    const float* __restrict__ bias, void* __restrict__ outp, int K, int Nn) {
  __shared__ unsigned short smem[16384];   // 32 KB: As[2] | Bs[2], then C 128x128
  unsigned short* As0 = smem;              // As[buf] = smem + buf*4096
  unsigned short* Bs0 = smem + 8192;       // Bs[buf] = smem+8192 + buf*4096
  const int tid = threadIdx.x;
  const int wave = tid >> 6, lane = tid & 63;
  const int nwg = gridDim.x * gridDim.y;
  const int wg = xcd_swz(blockIdx.x + gridDim.x * blockIdx.y, nwg);
  const int tm = (wg / gridDim.x) * 128, tn = (wg % gridDim.x) * 128;
  const int wm = (wave >> 1) * 64, wn = (wave & 1) * 64;
  const int lr = lane & 15, kq = lane >> 4;
  const int sw = (lr >> 1) & 3;
  const int koff = (kq ^ sw) * 8;
  const int c0 = tid, c1 = tid + 256;
  const int r0 = c0 >> 2, r1 = c1 >> 2;
  const int kc0 = ((c0 & 3) ^ ((r0 >> 1) & 3)) * 8;
  const int kc1 = ((c1 & 3) ^ ((r1 >> 1) & 3)) * 8;
  const size_t ga0 = (size_t)(tm + r0) * K + kc0;
  const size_t ga1 = (size_t)(tm + r1) * K + kc1;
  const size_t gb0 = (size_t)(tn + r0) * K + kc0;
  const size_t gb1 = (size_t)(tn + r1) * K + kc1;
  floatx4 acc[4][4] = {};
  auto stage = [&](int buf, int k0) {
    gl2lds16(A + ga0 + k0, As0 + buf * 4096 + c0 * 8);
    gl2lds16(A + ga1 + k0, As0 + buf * 4096 + c1 * 8);
    gl2lds16(W + gb0 + k0, Bs0 + buf * 4096 + c0 * 8);
    gl2lds16(W + gb1 + k0, Bs0 + buf * 4096 + c1 * 8);
  };
  const int nk = K >> 5;
  stage(0, 0);
  for (int it = 0; it < nk; it++) {
    const int cur = it & 1;
    __syncthreads();                       // drains stage(cur) (issued last iter)
    if (it + 1 < nk) stage(cur ^ 1, (it + 1) << 5);
    bf16x8 af[4], bq[4];
#pragma unroll
    for (int mi = 0; mi < 4; mi++)
      af[mi] = *(const bf16x8*)&As0[cur * 4096 + (wm + mi * 16 + lr) * 32 + koff];
#pragma unroll
    for (int ni = 0; ni < 4; ni++)
      bq[ni] = *(const bf16x8*)&Bs0[cur * 4096 + (wn + ni * 16 + lr) * 32 + koff];
#pragma unroll
    for (int mi = 0; mi < 4; mi++)
#pragma unroll
      for (int ni = 0; ni < 4; ni++)
        acc[mi][ni] = mfma_bf16(af[mi], bq[ni], acc[mi][ni]);
  }
  // ---- epilogue: acc -> LDS (bf16) -> coalesced stores ----
  __syncthreads();                         // staging LDS now dead, reuse as C
#pragma unroll
  for (int ni = 0; ni < 4; ni++) {
    const int lcol = wn + ni * 16 + lr;
    const float bv = bias[tn + lcol];
#pragma unroll
    for (int mi = 0; mi < 4; mi++) {
#pragma unroll
      for (int r = 0; r < 4; r++) {
        const int lrow = wm + mi * 16 + (lane >> 4) * 4 + r;
        float v = acc[mi][ni][r] + bv;
        if (MODE == 3) v = gelu_f(v);
        smem[lrow * 128 + lcol] = bf16u(v);
      }
    }
  }
  __syncthreads();
  const int tr = tid >> 4;                 // 0..15
  const int tc = (tid & 15) * 8;           // col offset (shorts), 16B chunks
#pragma unroll
  for (int p = 0; p < 8; p++) {
    const int lrow = p * 16 + tr;
    uint4 d = *(const uint4*)&smem[lrow * 128 + tc];
    *(uint4*)&((unsigned short*)outp)[(size_t)(tm + lrow) * Nn + tn + tc] = d;
  }
}

// ---- GEMM 128x128, split-K=2 via blockIdx.z, fp32 partial outputs ----
// z=0 -> p0 (with bias), z=1 -> p1 (no bias). Reduce happens in ln_fuse_k.
// fp32 stores are already full-line coalesced (16 lanes x 4B = 64B).
__global__ __launch_bounds__(256, 4) void gemm_sk(
    const unsigned short* __restrict__ A, const unsigned short* __restrict__ W,
    const float* __restrict__ bias, float* __restrict__ p0,
    float* __restrict__ p1, int K, int Nn) {
  __shared__ unsigned short As[2][128 * 32];
  __shared__ unsigned short Bs[2][128 * 32];
  const int tid = threadIdx.x;
  const int wave = tid >> 6, lane = tid & 63;
  const int nwg = gridDim.x * gridDim.y;
  const int wg = xcd_swz(blockIdx.x + gridDim.x * blockIdx.y, nwg);
  const int tm = (wg / gridDim.x) * 128, tn = (wg % gridDim.x) * 128;
  const int kz = blockIdx.z;
  const int kper = K >> 1;
  const int kbase = kz * kper;
  const int wm = (wave >> 1) * 64, wn = (wave & 1) * 64;
  const int lr = lane & 15, kq = lane >> 4;
  const int sw = (lr >> 1) & 3;
  const int koff = (kq ^ sw) * 8;
  const int c0 = tid, c1 = tid + 256;
  const int r0 = c0 >> 2, r1 = c1 >> 2;
  const int kc0 = ((c0 & 3) ^ ((r0 >> 1) & 3)) * 8;
  const int kc1 = ((c1 & 3) ^ ((r1 >> 1) & 3)) * 8;
  const size_t ga0 = (size_t)(tm + r0) * K + kc0 + kbase;
  const size_t ga1 = (size_t)(tm + r1) * K + kc1 + kbase;
  const size_t gb0 = (size_t)(tn + r0) * K + kc0 + kbase;
  const size_t gb1 = (size_t)(tn + r1) * K + kc1 + kbase;
  floatx4 acc[4][4] = {};
  auto stage = [&](int buf, int k0) {
    gl2lds16(A + ga0 + k0, &As[buf][c0 * 8]);
    gl2lds16(A + ga1 + k0, &As[buf][c1 * 8]);
    gl2lds16(W + gb0 + k0, &Bs[buf][c0 * 8]);
    gl2lds16(W + gb1 + k0, &Bs[buf][c1 * 8]);
  };
  const int nk = kper >> 5;
  stage(0, 0);
  for (int it = 0; it < nk; it++) {
    const int cur = it & 1;
    __syncthreads();
    if (it + 1 < nk) stage(cur ^ 1, (it + 1) << 5);
    bf16x8 af[4], bq[4];
#pragma unroll
    for (int mi = 0; mi < 4; mi++)
      af[mi] = *(const bf16x8*)&As[cur][(wm + mi * 16 + lr) * 32 + koff];
#pragma unroll
    for (int ni = 0; ni < 4; ni++)
      bq[ni] = *(const bf16x8*)&Bs[cur][(wn + ni * 16 + lr) * 32 + koff];
#pragma unroll
    for (int mi = 0; mi < 4; mi++)
#pragma unroll
      for (int ni = 0; ni < 4; ni++)
        acc[mi][ni] = mfma_bf16(af[mi], bq[ni], acc[mi][ni]);
  }
  float* __restrict__ po = kz ? p1 : p0;
  const int rbase = tm + wm + (lane >> 4) * 4;
  const int cbase = tn + wn + lr;
#pragma unroll
  for (int ni = 0; ni < 4; ni++) {
    const int col = cbase + ni * 16;
    const float bv = kz ? 0.0f : bias[col];
#pragma unroll
    for (int mi = 0; mi < 4; mi++) {
#pragma unroll
      for (int r = 0; r < 4; r++) {
        const int row = rbase + mi * 16 + r;
        po[(size_t)row * Nn + col] = acc[mi][ni][r] + bv;
      }
    }
  }
}

// ---- GEMM 64x128, double-buffered LDS (patch embed) ----
// MODE 1: out fp32 = acc + bias + pos[(row%196)*Nn + col]
template <int MODE>
__global__ __launch_bounds__(256, 4) void gemm64_bt(
    const unsigned short* __restrict__ A, const unsigned short* __restrict__ W,
    const float* __restrict__ bias, const float* __restrict__ aux,
    float* __restrict__ outp, int K, int Nn) {
  __shared__ unsigned short As[2][64 * 32];
  __shared__ unsigned short Bs[2][128 * 32];
  const int tid = threadIdx.x;
  const int wave = tid >> 6, lane = tid & 63;
  const int tm = blockIdx.y * 64, tn = blockIdx.x * 128;
  const int wm = (wave >> 1) * 32, wn = (wave & 1) * 64;
  const int lr = lane & 15, kq = lane >> 4;
  const int sw = (lr >> 1) & 3;
  const int koff = (kq ^ sw) * 8;
  const int ra = tid >> 2;
  const int kca = ((tid & 3) ^ ((ra >> 1) & 3)) * 8;
  const int c0 = tid, c1 = tid + 256;
  const int r0 = c0 >> 2, r1 = c1 >> 2;
  const int kc0 = ((c0 & 3) ^ ((r0 >> 1) & 3)) * 8;
  const int kc1 = ((c1 & 3) ^ ((r1 >> 1) & 3)) * 8;
  const size_t ga  = (size_t)(tm + ra) * K + kca;
  const size_t gb0 = (size_t)(tn + r0) * K + kc0;
  const size_t gb1 = (size_t)(tn + r1) * K + kc1;
  floatx4 acc[2][4] = {};
  auto stage = [&](int buf, int k0) {
    gl2lds16(A + ga + k0, &As[buf][tid * 8]);
    gl2lds16(W + gb0 + k0, &Bs[buf][c0 * 8]);
    gl2lds16(W + gb1 + k0, &Bs[buf][c1 * 8]);
  };
  const int nk = K >> 5;
  stage(0, 0);
  for (int it = 0; it < nk; it++) {
    const int cur = it & 1;
    __syncthreads();
    if (it + 1 < nk) stage(cur ^ 1, (it + 1) << 5);
    bf16x8 af[2], bq[4];
#pragma unroll
    for (int mi = 0; mi < 2; mi++)
      af[mi] = *(const bf16x8*)&As[cur][(wm + mi * 16 + lr) * 32 + koff];
#pragma unroll
    for (int ni = 0; ni < 4; ni++)
      bq[ni] = *(const bf16x8*)&Bs[cur][(wn + ni * 16 + lr) * 32 + koff];
#pragma unroll
    for (int mi = 0; mi < 2; mi++)
#pragma unroll
      for (int ni = 0; ni < 4; ni++)
        acc[mi][ni] = mfma_bf16(af[mi], bq[ni], acc[mi][ni]);
  }
  const int rbase = tm + wm + (lane >> 4) * 4;
  const int cbase = tn + wn + lr;
#pragma unroll
  for (int ni = 0; ni < 4; ni++) {
    const int col = cbase + ni * 16;
    const float bv = bias[col];
#pragma unroll
    for (int mi = 0; mi < 2; mi++) {
#pragma unroll
      for (int r = 0; r < 4; r++) {
        const int row = rbase + mi * 16 + r;
        float v = acc[mi][ni][r] + bv;
        float* hp = outp + (size_t)row * Nn + col;
        if (MODE == 1) *hp = v + aux[(size_t)(row % NN) * Nn + col];
        else           *hp = *hp + v;
      }
    }
  }
}

// ---- fused scores+softmax: per (bh, 32-row Q tile) -> P bf16 (rows x 224) ----
__global__ __launch_bounds__(256) void attn_sm_k(const unsigned short* __restrict__ qkv,
                                                 unsigned short* __restrict__ P) {
  __shared__ float S[32][232];             // +8 pad
  const int tid = threadIdx.x;
  const int bh = blockIdx.x;
  const int b = bh / HH, hh = bh % HH;
  const int i0 = blockIdx.y * 32;
  const int wave = tid >> 6, lane = tid & 63;
  const int lr = lane & 15, k8 = (lane >> 4) * 8;
  // 2x14 grid of 16x16 S tiles, 7 per wave
  for (int t = wave; t < 28; t += 4) {
    const int til = (t / 14) * 16, tj = (t % 14) * 16;
    const int iq = min(i0 + til + lr, NN - 1), jk = min(tj + lr, NN - 1);
    const unsigned short* qb = qkv + (size_t)(b * NN + iq) * 2304 + hh * 64 + k8;
    const unsigned short* kb = qkv + (size_t)(b * NN + jk) * 2304 + 768 + hh * 64 + k8;
    floatx4 acc = {0.f, 0.f, 0.f, 0.f};
    acc = mfma_bf16(*(const bf16x8*)qb, *(const bf16x8*)kb, acc);
    acc = mfma_bf16(*(const bf16x8*)(qb + 32), *(const bf16x8*)(kb + 32), acc);
#pragma unroll
    for (int r = 0; r < 4; r++)
      S[til + (lane >> 4) * 4 + r][tj + lr] = acc[r] * 0.125f;
  }
  __syncthreads();
  // softmax: 8 threads per row (row = tid>>3), cols strided by 8
  const int row = tid >> 3, sub = tid & 7;
  float v[28];
  float m = -1e30f;
#pragma unroll
  for (int t = 0; t < 28; t++) {
    const int c = sub + t * 8;
    v[t] = (c < NN) ? S[row][c] : -1e30f;
    m = fmaxf(m, v[t]);
  }
  m = fmaxf(m, __shfl_xor(m, 1));
  m = fmaxf(m, __shfl_xor(m, 2));
  m = fmaxf(m, __shfl_xor(m, 4));
  float s = 0.f;
#pragma unroll
  for (int t = 0; t < 28; t++) {
    v[t] = (sub + t * 8 < NN) ? __expf(v[t] - m) : 0.f;
    s += v[t];
  }
  s += __shfl_xor(s, 1);
  s += __shfl_xor(s, 2);
  s += __shfl_xor(s, 4);
  const float inv = 1.0f / s;
  const int gi = i0 + row;
  if (gi < NN) {
    unsigned short* prow = P + ((size_t)bh * NN + gi) * 224;
#pragma unroll
    for (int t = 0; t < 28; t++) prow[sub + t * 8] = bf16u(v[t] * inv);
  }
}

// ---- V transpose: Vt[bh][d][jp] = V[b,j,h,d], zero for j>=196 ----
__global__ __launch_bounds__(256) void vt_k(const unsigned short* __restrict__ qkv,
                                            unsigned short* __restrict__ Vt) {
  int idx = blockIdx.x * 256 + threadIdx.x;     // 384*64*224 exactly
  int j = idx % 224;
  int rest = idx / 224;
  int d = rest % 64, bh = rest / 64;
  int b = bh / HH, hh = bh % HH;
  unsigned short val = 0;
  if (j < NN) val = qkv[(size_t)(b * NN + j) * 2304 + 1536 + hh * 64 + d];
  Vt[idx] = val;
}

// ---- PV: o[b,i, h*64+d] = sum_j P[bh][i][j] * Vt[bh][d][j] ----
__global__ __launch_bounds__(256) void pv_k(const unsigned short* __restrict__ P,
                                            const unsigned short* __restrict__ Vt,
                                            unsigned short* __restrict__ o) {
  const int bh = blockIdx.x;
  const int b = bh / HH, hh = bh % HH;
  const int t = blockIdx.y * 4 + (threadIdx.x >> 6);
  const int it = t >> 2, dt = t & 3;
  const int lane = threadIdx.x & 63, lr = lane & 15, k8 = (lane >> 4) * 8;
  const int ip = min(it * 16 + lr, NN - 1);
  const unsigned short* pb = P + ((size_t)bh * NN + ip) * 224 + k8;
  const unsigned short* vb = Vt + ((size_t)bh * 64 + dt * 16 + lr) * 224 + k8;
  floatx4 acc = {0.f, 0.f, 0.f, 0.f};
#pragma unroll
  for (int k0 = 0; k0 < 224; k0 += 32)
    acc = mfma_bf16(*(const bf16x8*)(pb + k0), *(const bf16x8*)(vb + k0), acc);
#pragma unroll
  for (int r = 0; r < 4; r++) {
    int i = it * 16 + (lane >> 4) * 4 + r;
    if (i < NN)
      o[(size_t)(b * NN + i) * DD + hh * 64 + dt * 16 + lr] = bf16u(acc[r]);
  }
}

extern "C" void kernel_launch(void* const* d_in, const int* in_sizes, int n_in,
                              void* d_out, int out_size, void* d_ws, size_t ws_size,
                              hipStream_t stream) {
  const float* x       = (const float*)d_in[0];
  const float* patchw  = (const float*)d_in[1];
  const float* patchb  = (const float*)d_in[2];
  const float* pos     = (const float*)d_in[3];
  const float* ln1w    = (const float*)d_in[4];
  const float* ln1b    = (const float*)d_in[5];
  const float* qkvw    = (const float*)d_in[6];
  const float* qkvb    = (const float*)d_in[7];
  const float* projw   = (const float*)d_in[8];
  const float* projb   = (const float*)d_in[9];
  const float* ln2w    = (const float*)d_in[10];
  const float* ln2b    = (const float*)d_in[11];
  const float* fc1w    = (const float*)d_in[12];
  const float* fc1b    = (const float*)d_in[13];
  const float* fc2w    = (const float*)d_in[14];
  const float* fc2b    = (const float*)d_in[15];
  const float* lnfw    = (const float*)d_in[16];
  const float* lnfb    = (const float*)d_in[17];

  char* base = (char*)d_ws;
  size_t off = 0;
  auto alloc = [&](size_t bytes) {
    void* p = base + off;
    off = (off + bytes + 255) & ~(size_t)255;
    return p;
  };
  unsigned short* Wq  = (unsigned short*)alloc((size_t)LL * 2304 * 768 * 2);
  unsigned short* Wp  = (unsigned short*)alloc((size_t)LL * 768 * 768 * 2);
  unsigned short* W1  = (unsigned short*)alloc((size_t)LL * 3072 * 768 * 2);
  unsigned short* W2  = (unsigned short*)alloc((size_t)LL * 768 * 3072 * 2);
  unsigned short* Wpe = (unsigned short*)alloc((size_t)768 * 768 * 2);
  float*          h   = (float*)alloc((size_t)MM * DD * 4);
  unsigned short* y   = (unsigned short*)alloc((size_t)MM * DD * 2);
  unsigned short* qkv = (unsigned short*)alloc((size_t)MM * 2304 * 2);   // 28.9 MB
  unsigned short* g   = (unsigned short*)alloc((size_t)MM * FFF * 2);    // fc1 out
  unsigned short* P   = (unsigned short*)alloc((size_t)BHH * NN * 224 * 2); // 33.7 MB
  unsigned short* Vt  = (unsigned short*)alloc((size_t)BHH * 64 * 224 * 2);
  unsigned short* o   = (unsigned short*)alloc((size_t)MM * DD * 2);
  if (off > ws_size) return;  // workspace too small: fail loudly (wrong output)

  unsigned short* Aim = qkv;  // im2col buffer aliases qkv (dead by layer 0)
  // Split-K partial buffers (fp32, 19.27 MB each). Lifetimes: written by
  // gemm_sk (proj or fc2), read once by the immediately-following ln_fuse_k.
  // qkv is dead after vt_k; P is dead after pv_k — both regions free during
  // proj->ln2 and fc2->next-ln1 windows, and both hold >= MM*DD*4 bytes.
  float* pp0 = (float*)qkv;   // 19.27 <= 28.9 MB
  float* pp1 = (float*)P;     // 19.27 <= 33.7 MB

  auto cvt = [&](const float* src, unsigned short* dst, size_t n) {
    int n4 = (int)(n / 4);
    cvt4_k<<<dim3((n4 + 255) / 256), dim3(256), 0, stream>>>(
        (const float4*)src, (ushort4*)dst, n4);
  };
  cvt(qkvw, Wq, (size_t)LL * 2304 * 768);
  cvt(projw, Wp, (size_t)LL * 768 * 768);
  cvt(fc1w, W1, (size_t)LL * 3072 * 768);
  cvt(fc2w, W2, (size_t)LL * 768 * 3072);
  cvt(patchw, Wpe, (size_t)768 * 768);

  im2col_k<<<dim3(MM * DD / 256), dim3(256), 0, stream>>>(x, Aim);
  // patch embed GEMM: h = Aim @ Wpe^T + patch_b + pos
  gemm64_bt<1><<<dim3(6, 98), dim3(256), 0, stream>>>(Aim, Wpe, patchb, pos, h, 768, 768);

  // layer 0 ln1 (plain)
  ln_k<<<dim3(MM), dim3(256), 0, stream>>>(h, ln1w, ln1b, y);

  for (int l = 0; l < LL; l++) {
    gemm_bt<0><<<dim3(18, 49), dim3(256), 0, stream>>>(
        y, Wq + (size_t)l * 2304 * 768, qkvb + l * 2304, qkv, 768, 2304);
    attn_sm_k<<<dim3(BHH, 7), dim3(256), 0, stream>>>(qkv, P);
    vt_k<<<dim3(BHH * 64 * 224 / 256), dim3(256), 0, stream>>>(qkv, Vt);
    pv_k<<<dim3(BHH, 13), dim3(256), 0, stream>>>(P, Vt, o);
    // proj: 128x128 tile, split-K=2, fp32 partials (overwrite qkv/P regions)
    gemm_sk<<<dim3(6, 49, 2), dim3(256), 0, stream>>>(
        o, Wp + (size_t)l * 768 * 768, projb + l * 768, pp0, pp1, 768, 768);
    // h += pp0+pp1; y = ln2(h)
    ln_fuse_k<0><<<dim3(MM), dim3(256), 0, stream>>>(
        h, pp0, pp1, ln2w + l * 768, ln2b + l * 768, y);
    gemm_bt<3><<<dim3(24, 49), dim3(256), 0, stream>>>(
        y, W1 + (size_t)l * 3072 * 768, fc1b + l * 3072, g, 768, 3072);
    // fc2: 128x128 tile, split-K=2, fp32 partials
    gemm_sk<<<dim3(6, 49, 2), dim3(256), 0, stream>>>(
        g, W2 + (size_t)l * 768 * 3072, fc2b + l * 768, pp0, pp1, 3072, 768);
    if (l + 1 < LL) {
      // h += pp0+pp1; y = ln1_{l+1}(h)
      ln_fuse_k<0><<<dim3(MM), dim3(256), 0, stream>>>(
          h, pp0, pp1, ln1w + (l + 1) * 768, ln1b + (l + 1) * 768, y);
    } else {
      // final: out = lnf(h + pp0 + pp1), fp32
      ln_fuse_k<1><<<dim3(MM), dim3(256), 0, stream>>>(
          h, pp0, pp1, lnfw, lnfb, d_out);
    }
  }
}

// Round 5
// 3346.987 us; speedup vs baseline: 1.2634x; 1.0476x over previous
//
#include <hip/hip_runtime.h>
#include <hip/hip_bf16.h>
#include <math.h>

// ---- constants ----
#define BB    32
#define DD    768
#define LL    12
#define HH    12
#define NN    196
#define DHH   64
#define FFF   3072
#define MM    (BB * NN)      // 6272 tokens
#define BHH   (BB * HH)      // 384

typedef float  floatx4 __attribute__((ext_vector_type(4)));
typedef __bf16 bf16x8  __attribute__((ext_vector_type(8)));

#define DEV __device__ __forceinline__

DEV unsigned short bf16u(float v) {
  __hip_bfloat16 h = __float2bfloat16(v);
  return __builtin_bit_cast(unsigned short, h);
}

DEV floatx4 mfma_bf16(bf16x8 a, bf16x8 b, floatx4 c) {
  return __builtin_amdgcn_mfma_f32_16x16x32_bf16(a, b, c, 0, 0, 0);
}

DEV void gl2lds16(const void* g, void* l) {
  __builtin_amdgcn_global_load_lds(
      (const __attribute__((address_space(1))) void*)g,
      (__attribute__((address_space(3))) void*)l, 16, 0, 0);
}

// Fast erf (Abramowitz-Stegun 7.1.26, |err| <= 1.5e-7 — far below bf16 ulp).
// gelu(v) = 0.5 v (1 + erf(v/sqrt(2)))
DEV float gelu_f(float v) {
  float ax = fabsf(v) * 0.70710678118654752f;
  float t = 1.0f / (1.0f + 0.3275911f * ax);
  float poly = t * (0.254829592f +
              t * (-0.284496736f +
              t * (1.421413741f +
              t * (-1.453152027f +
              t * 1.061405429f))));
  float er = 1.0f - poly * __expf(-ax * ax);
  er = (v < 0.0f) ? -er : er;
  return 0.5f * v * (1.0f + er);
}

// Bijective XCD chunk transform (m204): orig%8 -> XCD; each XCD gets a
// contiguous range of linear tile ids (M-bands) -> L2 locality per XCD.
DEV int xcd_swz(int orig, int nwg) {
  int q = nwg >> 3, r = nwg & 7;
  int xcd = orig & 7, pos = orig >> 3;
  int base = (xcd < r) ? xcd * (q + 1) : r * (q + 1) + (xcd - r) * q;
  return base + pos;
}

// ---- fp32 -> bf16 conversion (vectorized) ----
__global__ __launch_bounds__(256) void cvt4_k(const float4* __restrict__ in,
                                              ushort4* __restrict__ out, int n4) {
  int i = blockIdx.x * 256 + threadIdx.x;
  if (i < n4) {
    float4 v = in[i];
    ushort4 o;
    o.x = bf16u(v.x); o.y = bf16u(v.y); o.z = bf16u(v.z); o.w = bf16u(v.w);
    out[i] = o;
  }
}

// ---- im2col for patch embed: x (32,3,224,224) -> A (6272, 768) bf16 ----
__global__ __launch_bounds__(256) void im2col_k(const float* __restrict__ x,
                                                unsigned short* __restrict__ A) {
  int idx = blockIdx.x * 256 + threadIdx.x;      // grid covers 6272*768 exactly
  int col = idx % DD;
  int token = idx / DD;
  int b = token / NN, p = token % NN;
  int pr = p / 14, pc = p % 14;
  int c = col >> 8, rm = col & 255, i = rm >> 4, j = rm & 15;
  float v = x[(((size_t)b * 3 + c) * 224 + pr * 16 + i) * 224 + pc * 16 + j];
  A[idx] = bf16u(v);
}

// ---- LayerNorm: h fp32 (M,768) -> y bf16 ----
__global__ __launch_bounds__(256) void ln_k(const float* __restrict__ x,
                                            const float* __restrict__ w,
                                            const float* __restrict__ bb,
                                            unsigned short* __restrict__ outp) {
  const int token = blockIdx.x, tid = threadIdx.x;
  const float* xr = x + (size_t)token * DD;
  float v0 = xr[tid], v1 = xr[tid + 256], v2 = xr[tid + 512];
  float s = v0 + v1 + v2;
  float ss = v0 * v0 + v1 * v1 + v2 * v2;
#pragma unroll
  for (int off = 32; off; off >>= 1) {
    s += __shfl_down(s, off);
    ss += __shfl_down(ss, off);
  }
  __shared__ float rs[4], rq[4];
  if ((tid & 63) == 0) { rs[tid >> 6] = s; rq[tid >> 6] = ss; }
  __syncthreads();
  float tot = rs[0] + rs[1] + rs[2] + rs[3];
  float tq  = rq[0] + rq[1] + rq[2] + rq[3];
  const float mean = tot * (1.0f / 768.0f);
  const float var  = tq * (1.0f / 768.0f) - mean * mean;
  const float rstd = rsqrtf(var + 1e-5f);
#pragma unroll
  for (int t = 0; t < 3; t++) {
    int col = tid + t * 256;
    float xv = (t == 0) ? v0 : (t == 1 ? v1 : v2);
    float yv = (xv - mean) * rstd * w[col] + bb[col];
    outp[(size_t)token * DD + col] = bf16u(yv);
  }
}

// ---- fused residual-reduce + LayerNorm:
// t = h + p0 + p1;  (FINAL==0) h = t, y = bf16(LN(t));  (FINAL==1) out = fp32 LN(t)
template <int FINAL>
__global__ __launch_bounds__(256) void ln_fuse_k(float* __restrict__ h,
    const float* __restrict__ p0, const float* __restrict__ p1,
    const float* __restrict__ w, const float* __restrict__ bb,
    void* __restrict__ outp) {
  const int token = blockIdx.x, tid = threadIdx.x;
  const size_t base = (size_t)token * DD;
  float v[3];
#pragma unroll
  for (int t = 0; t < 3; t++) {
    const int col = tid + t * 256;
    v[t] = h[base + col] + p0[base + col] + p1[base + col];
    if (!FINAL) h[base + col] = v[t];
  }
  float s = v[0] + v[1] + v[2];
  float ss = v[0] * v[0] + v[1] * v[1] + v[2] * v[2];
#pragma unroll
  for (int off = 32; off; off >>= 1) {
    s += __shfl_down(s, off);
    ss += __shfl_down(ss, off);
  }
  __shared__ float rs[4], rq[4];
  if ((tid & 63) == 0) { rs[tid >> 6] = s; rq[tid >> 6] = ss; }
  __syncthreads();
  float tot = rs[0] + rs[1] + rs[2] + rs[3];
  float tq  = rq[0] + rq[1] + rq[2] + rq[3];
  const float mean = tot * (1.0f / 768.0f);
  const float var  = tq * (1.0f / 768.0f) - mean * mean;
  const float rstd = rsqrtf(var + 1e-5f);
#pragma unroll
  for (int t = 0; t < 3; t++) {
    const int col = tid + t * 256;
    float yv = (v[t] - mean) * rstd * w[col] + bb[col];
    if (FINAL) ((float*)outp)[base + col] = yv;
    else       ((unsigned short*)outp)[base + col] = bf16u(yv);
  }
}

// LDS k-chunk XOR swizzle (verified: conflicts -> 0): LDS slot (row,s)
// holds global k-chunk s ^ ((row>>1)&3); staging permutes the GLOBAL source,
// reads apply the same XOR.

// ---- GEMM 128x128, double-buffered LDS ----
// MODE 0: out bf16 = acc + bias
// MODE 3: out bf16 = gelu(acc + bias)
// Epilogue: acc -> LDS (reuse staging buffers) -> coalesced 16B stores.
template <int MODE>
__global__ __launch_bounds__(256, 4) void gemm_bt(
    const unsigned short* __restrict__ A, const unsigned short* __restrict__ W,
    const float* __restrict__ bias, void* __restrict__ outp, int K, int Nn) {
  __shared__ unsigned short smem[16384];   // 32 KB: As[2] | Bs[2], then C 128x128
  unsigned short* As0 = smem;              // As[buf] = smem + buf*4096
  unsigned short* Bs0 = smem + 8192;       // Bs[buf] = smem+8192 + buf*4096
  const int tid = threadIdx.x;
  const int wave = tid >> 6, lane = tid & 63;
  const int nwg = gridDim.x * gridDim.y;
  const int wg = xcd_swz(blockIdx.x + gridDim.x * blockIdx.y, nwg);
  const int tm = (wg / gridDim.x) * 128, tn = (wg % gridDim.x) * 128;
  const int wm = (wave >> 1) * 64, wn = (wave & 1) * 64;
  const int lr = lane & 15, kq = lane >> 4;
  const int sw = (lr >> 1) & 3;
  const int koff = (kq ^ sw) * 8;
  const int c0 = tid, c1 = tid + 256;
  const int r0 = c0 >> 2, r1 = c1 >> 2;
  const int kc0 = ((c0 & 3) ^ ((r0 >> 1) & 3)) * 8;
  const int kc1 = ((c1 & 3) ^ ((r1 >> 1) & 3)) * 8;
  const size_t ga0 = (size_t)(tm + r0) * K + kc0;
  const size_t ga1 = (size_t)(tm + r1) * K + kc1;
  const size_t gb0 = (size_t)(tn + r0) * K + kc0;
  const size_t gb1 = (size_t)(tn + r1) * K + kc1;
  floatx4 acc[4][4] = {};
  auto stage = [&](int buf, int k0) {
    gl2lds16(A + ga0 + k0, As0 + buf * 4096 + c0 * 8);
    gl2lds16(A + ga1 + k0, As0 + buf * 4096 + c1 * 8);
    gl2lds16(W + gb0 + k0, Bs0 + buf * 4096 + c0 * 8);
    gl2lds16(W + gb1 + k0, Bs0 + buf * 4096 + c1 * 8);
  };
  const int nk = K >> 5;
  stage(0, 0);
  for (int it = 0; it < nk; it++) {
    const int cur = it & 1;
    __syncthreads();                       // drains stage(cur) (issued last iter)
    if (it + 1 < nk) stage(cur ^ 1, (it + 1) << 5);
    bf16x8 af[4], bq[4];
#pragma unroll
    for (int mi = 0; mi < 4; mi++)
      af[mi] = *(const bf16x8*)&As0[cur * 4096 + (wm + mi * 16 + lr) * 32 + koff];
#pragma unroll
    for (int ni = 0; ni < 4; ni++)
      bq[ni] = *(const bf16x8*)&Bs0[cur * 4096 + (wn + ni * 16 + lr) * 32 + koff];
#pragma unroll
    for (int mi = 0; mi < 4; mi++)
#pragma unroll
      for (int ni = 0; ni < 4; ni++)
        acc[mi][ni] = mfma_bf16(af[mi], bq[ni], acc[mi][ni]);
  }
  // ---- epilogue: acc -> LDS (bf16) -> coalesced stores ----
  __syncthreads();                         // staging LDS now dead, reuse as C
#pragma unroll
  for (int ni = 0; ni < 4; ni++) {
    const int lcol = wn + ni * 16 + lr;
    const float bv = bias[tn + lcol];
#pragma unroll
    for (int mi = 0; mi < 4; mi++) {
#pragma unroll
      for (int r = 0; r < 4; r++) {
        const int lrow = wm + mi * 16 + (lane >> 4) * 4 + r;
        float v = acc[mi][ni][r] + bv;
        if (MODE == 3) v = gelu_f(v);
        smem[lrow * 128 + lcol] = bf16u(v);
      }
    }
  }
  __syncthreads();
  const int tr = tid >> 4;                 // 0..15
  const int tc = (tid & 15) * 8;           // col offset (shorts), 16B chunks
#pragma unroll
  for (int p = 0; p < 8; p++) {
    const int lrow = p * 16 + tr;
    uint4 d = *(const uint4*)&smem[lrow * 128 + tc];
    *(uint4*)&((unsigned short*)outp)[(size_t)(tm + lrow) * Nn + tn + tc] = d;
  }
}

// ---- GEMM 128x128, split-K=2 via blockIdx.z, fp32 partial outputs ----
// z=0 -> p0 (with bias), z=1 -> p1 (no bias). Reduce happens in ln_fuse_k.
// fp32 stores are already full-line coalesced (16 lanes x 4B = 64B).
__global__ __launch_bounds__(256, 4) void gemm_sk(
    const unsigned short* __restrict__ A, const unsigned short* __restrict__ W,
    const float* __restrict__ bias, float* __restrict__ p0,
    float* __restrict__ p1, int K, int Nn) {
  __shared__ unsigned short As[2][128 * 32];
  __shared__ unsigned short Bs[2][128 * 32];
  const int tid = threadIdx.x;
  const int wave = tid >> 6, lane = tid & 63;
  const int nwg = gridDim.x * gridDim.y;
  const int wg = xcd_swz(blockIdx.x + gridDim.x * blockIdx.y, nwg);
  const int tm = (wg / gridDim.x) * 128, tn = (wg % gridDim.x) * 128;
  const int kz = blockIdx.z;
  const int kper = K >> 1;
  const int kbase = kz * kper;
  const int wm = (wave >> 1) * 64, wn = (wave & 1) * 64;
  const int lr = lane & 15, kq = lane >> 4;
  const int sw = (lr >> 1) & 3;
  const int koff = (kq ^ sw) * 8;
  const int c0 = tid, c1 = tid + 256;
  const int r0 = c0 >> 2, r1 = c1 >> 2;
  const int kc0 = ((c0 & 3) ^ ((r0 >> 1) & 3)) * 8;
  const int kc1 = ((c1 & 3) ^ ((r1 >> 1) & 3)) * 8;
  const size_t ga0 = (size_t)(tm + r0) * K + kc0 + kbase;
  const size_t ga1 = (size_t)(tm + r1) * K + kc1 + kbase;
  const size_t gb0 = (size_t)(tn + r0) * K + kc0 + kbase;
  const size_t gb1 = (size_t)(tn + r1) * K + kc1 + kbase;
  floatx4 acc[4][4] = {};
  auto stage = [&](int buf, int k0) {
    gl2lds16(A + ga0 + k0, &As[buf][c0 * 8]);
    gl2lds16(A + ga1 + k0, &As[buf][c1 * 8]);
    gl2lds16(W + gb0 + k0, &Bs[buf][c0 * 8]);
    gl2lds16(W + gb1 + k0, &Bs[buf][c1 * 8]);
  };
  const int nk = kper >> 5;
  stage(0, 0);
  for (int it = 0; it < nk; it++) {
    const int cur = it & 1;
    __syncthreads();
    if (it + 1 < nk) stage(cur ^ 1, (it + 1) << 5);
    bf16x8 af[4], bq[4];
#pragma unroll
    for (int mi = 0; mi < 4; mi++)
      af[mi] = *(const bf16x8*)&As[cur][(wm + mi * 16 + lr) * 32 + koff];
#pragma unroll
    for (int ni = 0; ni < 4; ni++)
      bq[ni] = *(const bf16x8*)&Bs[cur][(wn + ni * 16 + lr) * 32 + koff];
#pragma unroll
    for (int mi = 0; mi < 4; mi++)
#pragma unroll
      for (int ni = 0; ni < 4; ni++)
        acc[mi][ni] = mfma_bf16(af[mi], bq[ni], acc[mi][ni]);
  }
  float* __restrict__ po = kz ? p1 : p0;
  const int rbase = tm + wm + (lane >> 4) * 4;
  const int cbase = tn + wn + lr;
#pragma unroll
  for (int ni = 0; ni < 4; ni++) {
    const int col = cbase + ni * 16;
    const float bv = kz ? 0.0f : bias[col];
#pragma unroll
    for (int mi = 0; mi < 4; mi++) {
#pragma unroll
      for (int r = 0; r < 4; r++) {
        const int row = rbase + mi * 16 + r;
        po[(size_t)row * Nn + col] = acc[mi][ni][r] + bv;
      }
    }
  }
}

// ---- GEMM 64x128, double-buffered LDS (patch embed) ----
// MODE 1: out fp32 = acc + bias + pos[(row%196)*Nn + col]
template <int MODE>
__global__ __launch_bounds__(256, 4) void gemm64_bt(
    const unsigned short* __restrict__ A, const unsigned short* __restrict__ W,
    const float* __restrict__ bias, const float* __restrict__ aux,
    float* __restrict__ outp, int K, int Nn) {
  __shared__ unsigned short As[2][64 * 32];
  __shared__ unsigned short Bs[2][128 * 32];
  const int tid = threadIdx.x;
  const int wave = tid >> 6, lane = tid & 63;
  const int tm = blockIdx.y * 64, tn = blockIdx.x * 128;
  const int wm = (wave >> 1) * 32, wn = (wave & 1) * 64;
  const int lr = lane & 15, kq = lane >> 4;
  const int sw = (lr >> 1) & 3;
  const int koff = (kq ^ sw) * 8;
  const int ra = tid >> 2;
  const int kca = ((tid & 3) ^ ((ra >> 1) & 3)) * 8;
  const int c0 = tid, c1 = tid + 256;
  const int r0 = c0 >> 2, r1 = c1 >> 2;
  const int kc0 = ((c0 & 3) ^ ((r0 >> 1) & 3)) * 8;
  const int kc1 = ((c1 & 3) ^ ((r1 >> 1) & 3)) * 8;
  const size_t ga  = (size_t)(tm + ra) * K + kca;
  const size_t gb0 = (size_t)(tn + r0) * K + kc0;
  const size_t gb1 = (size_t)(tn + r1) * K + kc1;
  floatx4 acc[2][4] = {};
  auto stage = [&](int buf, int k0) {
    gl2lds16(A + ga + k0, &As[buf][tid * 8]);
    gl2lds16(W + gb0 + k0, &Bs[buf][c0 * 8]);
    gl2lds16(W + gb1 + k0, &Bs[buf][c1 * 8]);
  };
  const int nk = K >> 5;
  stage(0, 0);
  for (int it = 0; it < nk; it++) {
    const int cur = it & 1;
    __syncthreads();
    if (it + 1 < nk) stage(cur ^ 1, (it + 1) << 5);
    bf16x8 af[2], bq[4];
#pragma unroll
    for (int mi = 0; mi < 2; mi++)
      af[mi] = *(const bf16x8*)&As[cur][(wm + mi * 16 + lr) * 32 + koff];
#pragma unroll
    for (int ni = 0; ni < 4; ni++)
      bq[ni] = *(const bf16x8*)&Bs[cur][(wn + ni * 16 + lr) * 32 + koff];
#pragma unroll
    for (int mi = 0; mi < 2; mi++)
#pragma unroll
      for (int ni = 0; ni < 4; ni++)
        acc[mi][ni] = mfma_bf16(af[mi], bq[ni], acc[mi][ni]);
  }
  const int rbase = tm + wm + (lane >> 4) * 4;
  const int cbase = tn + wn + lr;
#pragma unroll
  for (int ni = 0; ni < 4; ni++) {
    const int col = cbase + ni * 16;
    const float bv = bias[col];
#pragma unroll
    for (int mi = 0; mi < 2; mi++) {
#pragma unroll
      for (int r = 0; r < 4; r++) {
        const int row = rbase + mi * 16 + r;
        float v = acc[mi][ni][r] + bv;
        float* hp = outp + (size_t)row * Nn + col;
        if (MODE == 1) *hp = v + aux[(size_t)(row % NN) * Nn + col];
        else           *hp = *hp + v;
      }
    }
  }
}

// ---- fused attention: scores + softmax + PV per (bh, 32-row Q tile) ----
// P never touches HBM: softmax output converted to bf16 in LDS and consumed
// directly as the PV MFMA A-operand (same fragment indexing pv_k used).
__global__ __launch_bounds__(256) void attn_fused_k(
    const unsigned short* __restrict__ qkv, const unsigned short* __restrict__ Vt,
    unsigned short* __restrict__ o) {
  __shared__ float S[32][232];                       // +8 pad (29.7 KB)
  __shared__ __align__(16) unsigned short Pl[32][232];  // bf16 P, +8 pad (14.8 KB)
  const int tid = threadIdx.x;
  const int bh = blockIdx.x;
  const int b = bh / HH, hh = bh % HH;
  const int i0 = blockIdx.y * 32;
  const int wave = tid >> 6, lane = tid & 63;
  const int lr = lane & 15, k8 = (lane >> 4) * 8;
  // --- scores: 2x14 grid of 16x16 S tiles, 7 per wave ---
  for (int t = wave; t < 28; t += 4) {
    const int til = (t / 14) * 16, tj = (t % 14) * 16;
    const int iq = min(i0 + til + lr, NN - 1), jk = min(tj + lr, NN - 1);
    const unsigned short* qb = qkv + (size_t)(b * NN + iq) * 2304 + hh * 64 + k8;
    const unsigned short* kb = qkv + (size_t)(b * NN + jk) * 2304 + 768 + hh * 64 + k8;
    floatx4 acc = {0.f, 0.f, 0.f, 0.f};
    acc = mfma_bf16(*(const bf16x8*)qb, *(const bf16x8*)kb, acc);
    acc = mfma_bf16(*(const bf16x8*)(qb + 32), *(const bf16x8*)(kb + 32), acc);
#pragma unroll
    for (int r = 0; r < 4; r++)
      S[til + (lane >> 4) * 4 + r][tj + lr] = acc[r] * 0.125f;
  }
  __syncthreads();
  // --- softmax: 8 threads per row (row = tid>>3), cols strided by 8 ---
  const int row = tid >> 3, sub = tid & 7;
  float v[28];
  float m = -1e30f;
#pragma unroll
  for (int t = 0; t < 28; t++) {
    const int c = sub + t * 8;
    v[t] = (c < NN) ? S[row][c] : -1e30f;
    m = fmaxf(m, v[t]);
  }
  m = fmaxf(m, __shfl_xor(m, 1));
  m = fmaxf(m, __shfl_xor(m, 2));
  m = fmaxf(m, __shfl_xor(m, 4));
  float s = 0.f;
#pragma unroll
  for (int t = 0; t < 28; t++) {
    v[t] = (sub + t * 8 < NN) ? __expf(v[t] - m) : 0.f;
    s += v[t];
  }
  s += __shfl_xor(s, 1);
  s += __shfl_xor(s, 2);
  s += __shfl_xor(s, 4);
  const float inv = 1.0f / s;
  // rows with global index >= NN hold finite garbage (clamped Q); their PV
  // results are discarded by the store guard below. cols >= NN are exact 0.
#pragma unroll
  for (int t = 0; t < 28; t++) Pl[row][sub + t * 8] = bf16u(v[t] * inv);
  __syncthreads();
  // --- PV: 8 output tiles (2 i x 4 d), 2 per wave, K=224 in 7 MFMA steps ---
#pragma unroll
  for (int w = 0; w < 2; w++) {
    const int tt = wave * 2 + w;
    const int it = tt >> 2, dt = tt & 3;
    const unsigned short* vb = Vt + ((size_t)bh * 64 + dt * 16 + lr) * 224 + k8;
    floatx4 acc = {0.f, 0.f, 0.f, 0.f};
#pragma unroll
    for (int k0 = 0; k0 < 224; k0 += 32)
      acc = mfma_bf16(*(const bf16x8*)&Pl[it * 16 + lr][k8 + k0],
                      *(const bf16x8*)(vb + k0), acc);
#pragma unroll
    for (int r = 0; r < 4; r++) {
      const int i = i0 + it * 16 + (lane >> 4) * 4 + r;
      if (i < NN)
        o[(size_t)(b * NN + i) * DD + hh * 64 + dt * 16 + lr] = bf16u(acc[r]);
    }
  }
}

// ---- V transpose: Vt[bh][d][jp] = V[b,j,h,d], zero for j>=196 ----
__global__ __launch_bounds__(256) void vt_k(const unsigned short* __restrict__ qkv,
                                            unsigned short* __restrict__ Vt) {
  int idx = blockIdx.x * 256 + threadIdx.x;     // 384*64*224 exactly
  int j = idx % 224;
  int rest = idx / 224;
  int d = rest % 64, bh = rest / 64;
  int b = bh / HH, hh = bh % HH;
  unsigned short val = 0;
  if (j < NN) val = qkv[(size_t)(b * NN + j) * 2304 + 1536 + hh * 64 + d];
  Vt[idx] = val;
}

extern "C" void kernel_launch(void* const* d_in, const int* in_sizes, int n_in,
                              void* d_out, int out_size, void* d_ws, size_t ws_size,
                              hipStream_t stream) {
  const float* x       = (const float*)d_in[0];
  const float* patchw  = (const float*)d_in[1];
  const float* patchb  = (const float*)d_in[2];
  const float* pos     = (const float*)d_in[3];
  const float* ln1w    = (const float*)d_in[4];
  const float* ln1b    = (const float*)d_in[5];
  const float* qkvw    = (const float*)d_in[6];
  const float* qkvb    = (const float*)d_in[7];
  const float* projw   = (const float*)d_in[8];
  const float* projb   = (const float*)d_in[9];
  const float* ln2w    = (const float*)d_in[10];
  const float* ln2b    = (const float*)d_in[11];
  const float* fc1w    = (const float*)d_in[12];
  const float* fc1b    = (const float*)d_in[13];
  const float* fc2w    = (const float*)d_in[14];
  const float* fc2b    = (const float*)d_in[15];
  const float* lnfw    = (const float*)d_in[16];
  const float* lnfb    = (const float*)d_in[17];

  char* base = (char*)d_ws;
  size_t off = 0;
  auto alloc = [&](size_t bytes) {
    void* p = base + off;
    off = (off + bytes + 255) & ~(size_t)255;
    return p;
  };
  unsigned short* Wq  = (unsigned short*)alloc((size_t)LL * 2304 * 768 * 2);
  unsigned short* Wp  = (unsigned short*)alloc((size_t)LL * 768 * 768 * 2);
  unsigned short* W1  = (unsigned short*)alloc((size_t)LL * 3072 * 768 * 2);
  unsigned short* W2  = (unsigned short*)alloc((size_t)LL * 768 * 3072 * 2);
  unsigned short* Wpe = (unsigned short*)alloc((size_t)768 * 768 * 2);
  float*          h   = (float*)alloc((size_t)MM * DD * 4);
  unsigned short* y   = (unsigned short*)alloc((size_t)MM * DD * 2);
  unsigned short* qkv = (unsigned short*)alloc((size_t)MM * 2304 * 2);   // 28.9 MB
  unsigned short* g   = (unsigned short*)alloc((size_t)MM * FFF * 2);    // fc1 out
  float*          pp1 = (float*)alloc((size_t)MM * DD * 4);              // split-K partial
  unsigned short* Vt  = (unsigned short*)alloc((size_t)BHH * 64 * 224 * 2);
  unsigned short* o   = (unsigned short*)alloc((size_t)MM * DD * 2);
  if (off > ws_size) return;  // workspace too small: fail loudly (wrong output)

  unsigned short* Aim = qkv;  // im2col buffer aliases qkv (dead by layer 0)
  // Split-K partial 0 aliases qkv (dead after attn_fused_k + vt_k consume it);
  // written by gemm_sk (proj or fc2), read by the immediately-following
  // ln_fuse_k before the next writer of the region (next layer's qkv GEMM).
  float* pp0 = (float*)qkv;   // 19.27 <= 28.9 MB

  auto cvt = [&](const float* src, unsigned short* dst, size_t n) {
    int n4 = (int)(n / 4);
    cvt4_k<<<dim3((n4 + 255) / 256), dim3(256), 0, stream>>>(
        (const float4*)src, (ushort4*)dst, n4);
  };
  cvt(qkvw, Wq, (size_t)LL * 2304 * 768);
  cvt(projw, Wp, (size_t)LL * 768 * 768);
  cvt(fc1w, W1, (size_t)LL * 3072 * 768);
  cvt(fc2w, W2, (size_t)LL * 768 * 3072);
  cvt(patchw, Wpe, (size_t)768 * 768);

  im2col_k<<<dim3(MM * DD / 256), dim3(256), 0, stream>>>(x, Aim);
  // patch embed GEMM: h = Aim @ Wpe^T + patch_b + pos
  gemm64_bt<1><<<dim3(6, 98), dim3(256), 0, stream>>>(Aim, Wpe, patchb, pos, h, 768, 768);

  // layer 0 ln1 (plain)
  ln_k<<<dim3(MM), dim3(256), 0, stream>>>(h, ln1w, ln1b, y);

  for (int l = 0; l < LL; l++) {
    gemm_bt<0><<<dim3(18, 49), dim3(256), 0, stream>>>(
        y, Wq + (size_t)l * 2304 * 768, qkvb + l * 2304, qkv, 768, 2304);
    vt_k<<<dim3(BHH * 64 * 224 / 256), dim3(256), 0, stream>>>(qkv, Vt);
    attn_fused_k<<<dim3(BHH, 7), dim3(256), 0, stream>>>(qkv, Vt, o);
    // proj: 128x128 tile, split-K=2, fp32 partials (pp0 overwrites qkv region)
    gemm_sk<<<dim3(6, 49, 2), dim3(256), 0, stream>>>(
        o, Wp + (size_t)l * 768 * 768, projb + l * 768, pp0, pp1, 768, 768);
    // h += pp0+pp1; y = ln2(h)
    ln_fuse_k<0><<<dim3(MM), dim3(256), 0, stream>>>(
        h, pp0, pp1, ln2w + l * 768, ln2b + l * 768, y);
    gemm_bt<3><<<dim3(24, 49), dim3(256), 0, stream>>>(
        y, W1 + (size_t)l * 3072 * 768, fc1b + l * 3072, g, 768, 3072);
    // fc2: 128x128 tile, split-K=2, fp32 partials
    gemm_sk<<<dim3(6, 49, 2), dim3(256), 0, stream>>>(
        g, W2 + (size_t)l * 768 * 3072, fc2b + l * 768, pp0, pp1, 3072, 768);
    if (l + 1 < LL) {
      // h += pp0+pp1; y = ln1_{l+1}(h)
      ln_fuse_k<0><<<dim3(MM), dim3(256), 0, stream>>>(
          h, pp0, pp1, ln1w + (l + 1) * 768, ln1b + (l + 1) * 768, y);
    } else {
      // final: out = lnf(h + pp0 + pp1), fp32
      ln_fuse_k<1><<<dim3(MM), dim3(256), 0, stream>>>(
          h, pp0, pp1, lnfw, lnfb, d_out);
    }
  }
}

// Round 6
// 3140.881 us; speedup vs baseline: 1.3463x; 1.0656x over previous
//
#include <hip/hip_runtime.h>
#include <hip/hip_bf16.h>
#include <math.h>

// ---- constants ----
#define BB    32
#define DD    768
#define LL    12
#define HH    12
#define NN    196
#define DHH   64
#define FFF   3072
#define MM    (BB * NN)      // 6272 tokens
#define BHH   (BB * HH)      // 384

typedef float  floatx4 __attribute__((ext_vector_type(4)));
typedef __bf16 bf16x8  __attribute__((ext_vector_type(8)));

#define DEV __device__ __forceinline__

DEV unsigned short bf16u(float v) {
  __hip_bfloat16 h = __float2bfloat16(v);
  return __builtin_bit_cast(unsigned short, h);
}

DEV floatx4 mfma_bf16(bf16x8 a, bf16x8 b, floatx4 c) {
  return __builtin_amdgcn_mfma_f32_16x16x32_bf16(a, b, c, 0, 0, 0);
}

DEV void gl2lds16(const void* g, void* l) {
  __builtin_amdgcn_global_load_lds(
      (const __attribute__((address_space(1))) void*)g,
      (__attribute__((address_space(3))) void*)l, 16, 0, 0);
}

// Fast erf (Abramowitz-Stegun 7.1.26, |err| <= 1.5e-7 — far below bf16 ulp).
DEV float gelu_f(float v) {
  float ax = fabsf(v) * 0.70710678118654752f;
  float t = 1.0f / (1.0f + 0.3275911f * ax);
  float poly = t * (0.254829592f +
              t * (-0.284496736f +
              t * (1.421413741f +
              t * (-1.453152027f +
              t * 1.061405429f))));
  float er = 1.0f - poly * __expf(-ax * ax);
  er = (v < 0.0f) ? -er : er;
  return 0.5f * v * (1.0f + er);
}

// Bijective XCD chunk transform (m204).
DEV int xcd_swz(int orig, int nwg) {
  int q = nwg >> 3, r = nwg & 7;
  int xcd = orig & 7, pos = orig >> 3;
  int base = (xcd < r) ? xcd * (q + 1) : r * (q + 1) + (xcd - r) * q;
  return base + pos;
}

// ---- fp32 -> bf16 conversion (vectorized) ----
__global__ __launch_bounds__(256) void cvt4_k(const float4* __restrict__ in,
                                              ushort4* __restrict__ out, int n4) {
  int i = blockIdx.x * 256 + threadIdx.x;
  if (i < n4) {
    float4 v = in[i];
    ushort4 o;
    o.x = bf16u(v.x); o.y = bf16u(v.y); o.z = bf16u(v.z); o.w = bf16u(v.w);
    out[i] = o;
  }
}

// ---- im2col for patch embed: x (32,3,224,224) -> A (6272, 768) bf16 ----
__global__ __launch_bounds__(256) void im2col_k(const float* __restrict__ x,
                                                unsigned short* __restrict__ A) {
  int idx = blockIdx.x * 256 + threadIdx.x;      // grid covers 6272*768 exactly
  int col = idx % DD;
  int token = idx / DD;
  int b = token / NN, p = token % NN;
  int pr = p / 14, pc = p % 14;
  int c = col >> 8, rm = col & 255, i = rm >> 4, j = rm & 15;
  float v = x[(((size_t)b * 3 + c) * 224 + pr * 16 + i) * 224 + pc * 16 + j];
  A[idx] = bf16u(v);
}

// ---- Vt pad zero: Vt[bh][d][196..223] = 0, once per launch ----
__global__ __launch_bounds__(256) void vtpad_k(unsigned short* __restrict__ Vt) {
  int idx = blockIdx.x * 256 + threadIdx.x;     // 384*64*28 exactly
  int jj = idx % 28, rest = idx / 28;
  Vt[(size_t)rest * 224 + 196 + jj] = 0;
}

// ---- wave-parallel LayerNorm: x fp32 (M,768) -> y bf16. 4 tokens/block. ----
__global__ __launch_bounds__(256) void lnw_k(const float* __restrict__ x,
                                             const float* __restrict__ w,
                                             const float* __restrict__ bb,
                                             unsigned short* __restrict__ outp) {
  const int token = blockIdx.x * 4 + (threadIdx.x >> 6);
  const int lane = threadIdx.x & 63;
  const size_t base = (size_t)token * DD;
  const float4* x4 = (const float4*)(x + base);
  const float4* w4 = (const float4*)w;
  const float4* b4 = (const float4*)bb;
  float4 v[3];
  float s = 0.f, ss = 0.f;
#pragma unroll
  for (int j = 0; j < 3; j++) {
    float4 t = x4[lane + j * 64];
    v[j] = t;
    s += t.x + t.y + t.z + t.w;
    ss += t.x * t.x + t.y * t.y + t.z * t.z + t.w * t.w;
  }
#pragma unroll
  for (int off = 32; off; off >>= 1) {
    s += __shfl_xor(s, off);
    ss += __shfl_xor(ss, off);
  }
  const float mean = s * (1.0f / 768.0f);
  const float var  = ss * (1.0f / 768.0f) - mean * mean;
  const float rstd = rsqrtf(var + 1e-5f);
#pragma unroll
  for (int j = 0; j < 3; j++) {
    const int c4 = lane + j * 64;
    float4 wv = w4[c4], bv = b4[c4];
    ushort4 o;
    o.x = bf16u((v[j].x - mean) * rstd * wv.x + bv.x);
    o.y = bf16u((v[j].y - mean) * rstd * wv.y + bv.y);
    o.z = bf16u((v[j].z - mean) * rstd * wv.z + bv.z);
    o.w = bf16u((v[j].w - mean) * rstd * wv.w + bv.w);
    ((ushort4*)((unsigned short*)outp + base))[c4] = o;
  }
}

// ---- fused residual-reduce + LayerNorm (wave-parallel, 4 tokens/block):
// t = h + p0 + p1;  (FINAL==0) h = t, y = bf16(LN(t));  (FINAL==1) out = fp32 LN(t)
template <int FINAL>
__global__ __launch_bounds__(256) void ln_fuse_k(float* __restrict__ h,
    const float* __restrict__ p0, const float* __restrict__ p1,
    const float* __restrict__ w, const float* __restrict__ bb,
    void* __restrict__ outp) {
  const int token = blockIdx.x * 4 + (threadIdx.x >> 6);
  const int lane = threadIdx.x & 63;
  const size_t base = (size_t)token * DD;
  const float4* h4 = (const float4*)(h + base);
  const float4* p04 = (const float4*)(p0 + base);
  const float4* p14 = (const float4*)(p1 + base);
  const float4* w4 = (const float4*)w;
  const float4* b4 = (const float4*)bb;
  float4 v[3];
  float s = 0.f, ss = 0.f;
#pragma unroll
  for (int j = 0; j < 3; j++) {
    const int c4 = lane + j * 64;
    float4 a = h4[c4], b2 = p04[c4], c2 = p14[c4];
    float4 t;
    t.x = a.x + b2.x + c2.x; t.y = a.y + b2.y + c2.y;
    t.z = a.z + b2.z + c2.z; t.w = a.w + b2.w + c2.w;
    v[j] = t;
    s += t.x + t.y + t.z + t.w;
    ss += t.x * t.x + t.y * t.y + t.z * t.z + t.w * t.w;
    if (!FINAL) ((float4*)(h + base))[c4] = t;
  }
#pragma unroll
  for (int off = 32; off; off >>= 1) {
    s += __shfl_xor(s, off);
    ss += __shfl_xor(ss, off);
  }
  const float mean = s * (1.0f / 768.0f);
  const float var  = ss * (1.0f / 768.0f) - mean * mean;
  const float rstd = rsqrtf(var + 1e-5f);
#pragma unroll
  for (int j = 0; j < 3; j++) {
    const int c4 = lane + j * 64;
    float4 wv = w4[c4], bv = b4[c4];
    float4 yv;
    yv.x = (v[j].x - mean) * rstd * wv.x + bv.x;
    yv.y = (v[j].y - mean) * rstd * wv.y + bv.y;
    yv.z = (v[j].z - mean) * rstd * wv.z + bv.z;
    yv.w = (v[j].w - mean) * rstd * wv.w + bv.w;
    if (FINAL) {
      ((float4*)((float*)outp + base))[c4] = yv;
    } else {
      ushort4 o;
      o.x = bf16u(yv.x); o.y = bf16u(yv.y); o.z = bf16u(yv.z); o.w = bf16u(yv.w);
      ((ushort4*)((unsigned short*)outp + base))[c4] = o;
    }
  }
}

// LDS k-chunk XOR swizzle (verified: conflicts -> 0): LDS slot (row,s)
// holds global k-chunk s ^ ((row>>1)&3); staging permutes the GLOBAL source,
// reads apply the same XOR.

// ---- GEMM 128x128, double-buffered LDS ----
// MODE 0: out bf16 = acc + bias
// MODE 3: out bf16 = gelu(acc + bias)
// MODE 4: qkv mode — Q/K tiles (tn<1536) write to qkv normally; V tiles
//         (tn>=1536, tile-aligned) write TRANSPOSED into Vt[bh][d][j].
template <int MODE>
__global__ __launch_bounds__(256, 4) void gemm_bt(
    const unsigned short* __restrict__ A, const unsigned short* __restrict__ W,
    const float* __restrict__ bias, void* __restrict__ outp,
    unsigned short* __restrict__ vtp, int K, int Nn) {
  __shared__ unsigned short smem[17408];   // 34 KB: staging 2x(4K+4K), C-tile reuse
  unsigned short* As0 = smem;              // As[buf] = smem + buf*4096
  unsigned short* Bs0 = smem + 8192;       // Bs[buf] = smem+8192 + buf*4096
  const int tid = threadIdx.x;
  const int wave = tid >> 6, lane = tid & 63;
  const int nwg = gridDim.x * gridDim.y;
  const int wg = xcd_swz(blockIdx.x + gridDim.x * blockIdx.y, nwg);
  const int tm = (wg / gridDim.x) * 128, tn = (wg % gridDim.x) * 128;
  const int wm = (wave >> 1) * 64, wn = (wave & 1) * 64;
  const int lr = lane & 15, kq = lane >> 4;
  const int sw = (lr >> 1) & 3;
  const int koff = (kq ^ sw) * 8;
  const int c0 = tid, c1 = tid + 256;
  const int r0 = c0 >> 2, r1 = c1 >> 2;
  const int kc0 = ((c0 & 3) ^ ((r0 >> 1) & 3)) * 8;
  const int kc1 = ((c1 & 3) ^ ((r1 >> 1) & 3)) * 8;
  const size_t ga0 = (size_t)(tm + r0) * K + kc0;
  const size_t ga1 = (size_t)(tm + r1) * K + kc1;
  const size_t gb0 = (size_t)(tn + r0) * K + kc0;
  const size_t gb1 = (size_t)(tn + r1) * K + kc1;
  floatx4 acc[4][4] = {};
  auto stage = [&](int buf, int k0) {
    gl2lds16(A + ga0 + k0, As0 + buf * 4096 + c0 * 8);
    gl2lds16(A + ga1 + k0, As0 + buf * 4096 + c1 * 8);
    gl2lds16(W + gb0 + k0, Bs0 + buf * 4096 + c0 * 8);
    gl2lds16(W + gb1 + k0, Bs0 + buf * 4096 + c1 * 8);
  };
  const int nk = K >> 5;
  stage(0, 0);
  for (int it = 0; it < nk; it++) {
    const int cur = it & 1;
    __syncthreads();                       // drains stage(cur) (issued last iter)
    if (it + 1 < nk) stage(cur ^ 1, (it + 1) << 5);
    bf16x8 af[4], bq[4];
#pragma unroll
    for (int mi = 0; mi < 4; mi++)
      af[mi] = *(const bf16x8*)&As0[cur * 4096 + (wm + mi * 16 + lr) * 32 + koff];
#pragma unroll
    for (int ni = 0; ni < 4; ni++)
      bq[ni] = *(const bf16x8*)&Bs0[cur * 4096 + (wn + ni * 16 + lr) * 32 + koff];
#pragma unroll
    for (int mi = 0; mi < 4; mi++)
#pragma unroll
      for (int ni = 0; ni < 4; ni++)
        acc[mi][ni] = mfma_bf16(af[mi], bq[ni], acc[mi][ni]);
  }
  __syncthreads();                         // staging LDS now dead, reuse as C
  const bool vtile = (MODE == 4) && (tn >= 1536);
  if (vtile) {
    // V tile: bias-add, store TRANSPOSED Ct[col][row] (stride 136, pad 8)
#pragma unroll
    for (int ni = 0; ni < 4; ni++) {
      const int lcol = wn + ni * 16 + lr;
      const float bv = bias[tn + lcol];
#pragma unroll
      for (int mi = 0; mi < 4; mi++) {
#pragma unroll
        for (int r = 0; r < 4; r++) {
          const int lrow = wm + mi * 16 + (lane >> 4) * 4 + r;
          smem[lcol * 136 + lrow] = bf16u(acc[mi][ni][r] + bv);
        }
      }
    }
    __syncthreads();
    // coalesced Vt writes: 2048 chunks of 8 tokens, 8 per thread
    const int vbase = tn - 1536;
#pragma unroll
    for (int sch = 0; sch < 8; sch++) {
      const int c = tid + sch * 256;
      const int col = c >> 4, j0 = (c & 15) * 8;
      const int hh = (vbase + col) >> 6, d = (vbase + col) & 63;
      const int row0 = tm + j0;
      const int b0 = row0 / NN, jA = row0 % NN;
      if (jA + 7 < NN) {
        // same batch, contiguous j — two 8B stores (jA % 4 == 0 -> 8B aligned)
        unsigned short* dst = vtp + ((size_t)(b0 * HH + hh) * 64 + d) * 224 + jA;
        *(ushort4*)dst = *(const ushort4*)&smem[col * 136 + j0];
        *(ushort4*)(dst + 4) = *(const ushort4*)&smem[col * 136 + j0 + 4];
      } else {
#pragma unroll
        for (int k = 0; k < 8; k++) {
          const int row = row0 + k;
          const int b = row / NN, j = row % NN;
          vtp[((size_t)(b * HH + hh) * 64 + d) * 224 + j] = smem[col * 136 + j0 + k];
        }
      }
    }
  } else {
    // normal path: C row-major in LDS, coalesced 16B stores
#pragma unroll
    for (int ni = 0; ni < 4; ni++) {
      const int lcol = wn + ni * 16 + lr;
      const float bv = bias[tn + lcol];
#pragma unroll
      for (int mi = 0; mi < 4; mi++) {
#pragma unroll
        for (int r = 0; r < 4; r++) {
          const int lrow = wm + mi * 16 + (lane >> 4) * 4 + r;
          float v = acc[mi][ni][r] + bv;
          if (MODE == 3) v = gelu_f(v);
          smem[lrow * 128 + lcol] = bf16u(v);
        }
      }
    }
    __syncthreads();
    const int tr = tid >> 4;               // 0..15
    const int tc = (tid & 15) * 8;         // col offset (shorts), 16B chunks
#pragma unroll
    for (int p = 0; p < 8; p++) {
      const int lrow = p * 16 + tr;
      uint4 dv = *(const uint4*)&smem[lrow * 128 + tc];
      *(uint4*)&((unsigned short*)outp)[(size_t)(tm + lrow) * Nn + tn + tc] = dv;
    }
  }
}

// ---- GEMM 128x128, split-K=2 via blockIdx.z, fp32 partial outputs ----
// z=0 -> p0 (with bias), z=1 -> p1 (no bias). Reduce happens in ln_fuse_k.
__global__ __launch_bounds__(256, 4) void gemm_sk(
    const unsigned short* __restrict__ A, const unsigned short* __restrict__ W,
    const float* __restrict__ bias, float* __restrict__ p0,
    float* __restrict__ p1, int K, int Nn) {
  __shared__ unsigned short As[2][128 * 32];
  __shared__ unsigned short Bs[2][128 * 32];
  const int tid = threadIdx.x;
  const int wave = tid >> 6, lane = tid & 63;
  const int nwg = gridDim.x * gridDim.y;
  const int wg = xcd_swz(blockIdx.x + gridDim.x * blockIdx.y, nwg);
  const int tm = (wg / gridDim.x) * 128, tn = (wg % gridDim.x) * 128;
  const int kz = blockIdx.z;
  const int kper = K >> 1;
  const int kbase = kz * kper;
  const int wm = (wave >> 1) * 64, wn = (wave & 1) * 64;
  const int lr = lane & 15, kq = lane >> 4;
  const int sw = (lr >> 1) & 3;
  const int koff = (kq ^ sw) * 8;
  const int c0 = tid, c1 = tid + 256;
  const int r0 = c0 >> 2, r1 = c1 >> 2;
  const int kc0 = ((c0 & 3) ^ ((r0 >> 1) & 3)) * 8;
  const int kc1 = ((c1 & 3) ^ ((r1 >> 1) & 3)) * 8;
  const size_t ga0 = (size_t)(tm + r0) * K + kc0 + kbase;
  const size_t ga1 = (size_t)(tm + r1) * K + kc1 + kbase;
  const size_t gb0 = (size_t)(tn + r0) * K + kc0 + kbase;
  const size_t gb1 = (size_t)(tn + r1) * K + kc1 + kbase;
  floatx4 acc[4][4] = {};
  auto stage = [&](int buf, int k0) {
    gl2lds16(A + ga0 + k0, &As[buf][c0 * 8]);
    gl2lds16(A + ga1 + k0, &As[buf][c1 * 8]);
    gl2lds16(W + gb0 + k0, &Bs[buf][c0 * 8]);
    gl2lds16(W + gb1 + k0, &Bs[buf][c1 * 8]);
  };
  const int nk = kper >> 5;
  stage(0, 0);
  for (int it = 0; it < nk; it++) {
    const int cur = it & 1;
    __syncthreads();
    if (it + 1 < nk) stage(cur ^ 1, (it + 1) << 5);
    bf16x8 af[4], bq[4];
#pragma unroll
    for (int mi = 0; mi < 4; mi++)
      af[mi] = *(const bf16x8*)&As[cur][(wm + mi * 16 + lr) * 32 + koff];
#pragma unroll
    for (int ni = 0; ni < 4; ni++)
      bq[ni] = *(const bf16x8*)&Bs[cur][(wn + ni * 16 + lr) * 32 + koff];
#pragma unroll
    for (int mi = 0; mi < 4; mi++)
#pragma unroll
      for (int ni = 0; ni < 4; ni++)
        acc[mi][ni] = mfma_bf16(af[mi], bq[ni], acc[mi][ni]);
  }
  float* __restrict__ po = kz ? p1 : p0;
  const int rbase = tm + wm + (lane >> 4) * 4;
  const int cbase = tn + wn + lr;
#pragma unroll
  for (int ni = 0; ni < 4; ni++) {
    const int col = cbase + ni * 16;
    const float bv = kz ? 0.0f : bias[col];
#pragma unroll
    for (int mi = 0; mi < 4; mi++) {
#pragma unroll
      for (int r = 0; r < 4; r++) {
        const int row = rbase + mi * 16 + r;
        po[(size_t)row * Nn + col] = acc[mi][ni][r] + bv;
      }
    }
  }
}

// ---- GEMM 64x128, double-buffered LDS (patch embed) ----
// MODE 1: out fp32 = acc + bias + pos[(row%196)*Nn + col]
template <int MODE>
__global__ __launch_bounds__(256, 4) void gemm64_bt(
    const unsigned short* __restrict__ A, const unsigned short* __restrict__ W,
    const float* __restrict__ bias, const float* __restrict__ aux,
    float* __restrict__ outp, int K, int Nn) {
  __shared__ unsigned short As[2][64 * 32];
  __shared__ unsigned short Bs[2][128 * 32];
  const int tid = threadIdx.x;
  const int wave = tid >> 6, lane = tid & 63;
  const int tm = blockIdx.y * 64, tn = blockIdx.x * 128;
  const int wm = (wave >> 1) * 32, wn = (wave & 1) * 64;
  const int lr = lane & 15, kq = lane >> 4;
  const int sw = (lr >> 1) & 3;
  const int koff = (kq ^ sw) * 8;
  const int ra = tid >> 2;
  const int kca = ((tid & 3) ^ ((ra >> 1) & 3)) * 8;
  const int c0 = tid, c1 = tid + 256;
  const int r0 = c0 >> 2, r1 = c1 >> 2;
  const int kc0 = ((c0 & 3) ^ ((r0 >> 1) & 3)) * 8;
  const int kc1 = ((c1 & 3) ^ ((r1 >> 1) & 3)) * 8;
  const size_t ga  = (size_t)(tm + ra) * K + kca;
  const size_t gb0 = (size_t)(tn + r0) * K + kc0;
  const size_t gb1 = (size_t)(tn + r1) * K + kc1;
  floatx4 acc[2][4] = {};
  auto stage = [&](int buf, int k0) {
    gl2lds16(A + ga + k0, &As[buf][tid * 8]);
    gl2lds16(W + gb0 + k0, &Bs[buf][c0 * 8]);
    gl2lds16(W + gb1 + k0, &Bs[buf][c1 * 8]);
  };
  const int nk = K >> 5;
  stage(0, 0);
  for (int it = 0; it < nk; it++) {
    const int cur = it & 1;
    __syncthreads();
    if (it + 1 < nk) stage(cur ^ 1, (it + 1) << 5);
    bf16x8 af[2], bq[4];
#pragma unroll
    for (int mi = 0; mi < 2; mi++)
      af[mi] = *(const bf16x8*)&As[cur][(wm + mi * 16 + lr) * 32 + koff];
#pragma unroll
    for (int ni = 0; ni < 4; ni++)
      bq[ni] = *(const bf16x8*)&Bs[cur][(wn + ni * 16 + lr) * 32 + koff];
#pragma unroll
    for (int mi = 0; mi < 2; mi++)
#pragma unroll
      for (int ni = 0; ni < 4; ni++)
        acc[mi][ni] = mfma_bf16(af[mi], bq[ni], acc[mi][ni]);
  }
  const int rbase = tm + wm + (lane >> 4) * 4;
  const int cbase = tn + wn + lr;
#pragma unroll
  for (int ni = 0; ni < 4; ni++) {
    const int col = cbase + ni * 16;
    const float bv = bias[col];
#pragma unroll
    for (int mi = 0; mi < 2; mi++) {
#pragma unroll
      for (int r = 0; r < 4; r++) {
        const int row = rbase + mi * 16 + r;
        float v = acc[mi][ni][r] + bv;
        float* hp = outp + (size_t)row * Nn + col;
        if (MODE == 1) *hp = v + aux[(size_t)(row % NN) * Nn + col];
        else           *hp = *hp + v;
      }
    }
  }
}

// ---- fused attention: scores + softmax + PV per (bh, 32-row Q tile) ----
__global__ __launch_bounds__(256) void attn_fused_k(
    const unsigned short* __restrict__ qkv, const unsigned short* __restrict__ Vt,
    unsigned short* __restrict__ o) {
  __shared__ float S[32][232];                       // +8 pad (29.7 KB)
  __shared__ __align__(16) unsigned short Pl[32][232];  // bf16 P, +8 pad (14.8 KB)
  const int tid = threadIdx.x;
  const int bh = blockIdx.x;
  const int b = bh / HH, hh = bh % HH;
  const int i0 = blockIdx.y * 32;
  const int wave = tid >> 6, lane = tid & 63;
  const int lr = lane & 15, k8 = (lane >> 4) * 8;
  // --- scores: 2x14 grid of 16x16 S tiles, 7 per wave ---
  for (int t = wave; t < 28; t += 4) {
    const int til = (t / 14) * 16, tj = (t % 14) * 16;
    const int iq = min(i0 + til + lr, NN - 1), jk = min(tj + lr, NN - 1);
    const unsigned short* qb = qkv + (size_t)(b * NN + iq) * 2304 + hh * 64 + k8;
    const unsigned short* kb = qkv + (size_t)(b * NN + jk) * 2304 + 768 + hh * 64 + k8;
    floatx4 acc = {0.f, 0.f, 0.f, 0.f};
    acc = mfma_bf16(*(const bf16x8*)qb, *(const bf16x8*)kb, acc);
    acc = mfma_bf16(*(const bf16x8*)(qb + 32), *(const bf16x8*)(kb + 32), acc);
#pragma unroll
    for (int r = 0; r < 4; r++)
      S[til + (lane >> 4) * 4 + r][tj + lr] = acc[r] * 0.125f;
  }
  __syncthreads();
  // --- softmax: 8 threads per row (row = tid>>3), cols strided by 8 ---
  const int row = tid >> 3, sub = tid & 7;
  float v[28];
  float m = -1e30f;
#pragma unroll
  for (int t = 0; t < 28; t++) {
    const int c = sub + t * 8;
    v[t] = (c < NN) ? S[row][c] : -1e30f;
    m = fmaxf(m, v[t]);
  }
  m = fmaxf(m, __shfl_xor(m, 1));
  m = fmaxf(m, __shfl_xor(m, 2));
  m = fmaxf(m, __shfl_xor(m, 4));
  float s = 0.f;
#pragma unroll
  for (int t = 0; t < 28; t++) {
    v[t] = (sub + t * 8 < NN) ? __expf(v[t] - m) : 0.f;
    s += v[t];
  }
  s += __shfl_xor(s, 1);
  s += __shfl_xor(s, 2);
  s += __shfl_xor(s, 4);
  const float inv = 1.0f / s;
#pragma unroll
  for (int t = 0; t < 28; t++) Pl[row][sub + t * 8] = bf16u(v[t] * inv);
  __syncthreads();
  // --- PV: 8 output tiles (2 i x 4 d), 2 per wave, K=224 in 7 MFMA steps ---
#pragma unroll
  for (int w = 0; w < 2; w++) {
    const int tt = wave * 2 + w;
    const int it = tt >> 2, dt = tt & 3;
    const unsigned short* vb = Vt + ((size_t)bh * 64 + dt * 16 + lr) * 224 + k8;
    floatx4 acc = {0.f, 0.f, 0.f, 0.f};
#pragma unroll
    for (int k0 = 0; k0 < 224; k0 += 32)
      acc = mfma_bf16(*(const bf16x8*)&Pl[it * 16 + lr][k8 + k0],
                      *(const bf16x8*)(vb + k0), acc);
#pragma unroll
    for (int r = 0; r < 4; r++) {
      const int i = i0 + it * 16 + (lane >> 4) * 4 + r;
      if (i < NN)
        o[(size_t)(b * NN + i) * DD + hh * 64 + dt * 16 + lr] = bf16u(acc[r]);
    }
  }
}

extern "C" void kernel_launch(void* const* d_in, const int* in_sizes, int n_in,
                              void* d_out, int out_size, void* d_ws, size_t ws_size,
                              hipStream_t stream) {
  const float* x       = (const float*)d_in[0];
  const float* patchw  = (const float*)d_in[1];
  const float* patchb  = (const float*)d_in[2];
  const float* pos     = (const float*)d_in[3];
  const float* ln1w    = (const float*)d_in[4];
  const float* ln1b    = (const float*)d_in[5];
  const float* qkvw    = (const float*)d_in[6];
  const float* qkvb    = (const float*)d_in[7];
  const float* projw   = (const float*)d_in[8];
  const float* projb   = (const float*)d_in[9];
  const float* ln2w    = (const float*)d_in[10];
  const float* ln2b    = (const float*)d_in[11];
  const float* fc1w    = (const float*)d_in[12];
  const float* fc1b    = (const float*)d_in[13];
  const float* fc2w    = (const float*)d_in[14];
  const float* fc2b    = (const float*)d_in[15];
  const float* lnfw    = (const float*)d_in[16];
  const float* lnfb    = (const float*)d_in[17];

  char* base = (char*)d_ws;
  size_t off = 0;
  auto alloc = [&](size_t bytes) {
    void* p = base + off;
    off = (off + bytes + 255) & ~(size_t)255;
    return p;
  };
  unsigned short* Wq  = (unsigned short*)alloc((size_t)LL * 2304 * 768 * 2);
  unsigned short* Wp  = (unsigned short*)alloc((size_t)LL * 768 * 768 * 2);
  unsigned short* W1  = (unsigned short*)alloc((size_t)LL * 3072 * 768 * 2);
  unsigned short* W2  = (unsigned short*)alloc((size_t)LL * 768 * 3072 * 2);
  unsigned short* Wpe = (unsigned short*)alloc((size_t)768 * 768 * 2);
  float*          h   = (float*)alloc((size_t)MM * DD * 4);
  unsigned short* y   = (unsigned short*)alloc((size_t)MM * DD * 2);
  unsigned short* qkv = (unsigned short*)alloc((size_t)MM * 2304 * 2);   // 28.9 MB
  unsigned short* g   = (unsigned short*)alloc((size_t)MM * FFF * 2);    // fc1 out
  float*          pp1 = (float*)alloc((size_t)MM * DD * 4);              // split-K partial
  unsigned short* Vt  = (unsigned short*)alloc((size_t)BHH * 64 * 224 * 2);
  unsigned short* o   = (unsigned short*)alloc((size_t)MM * DD * 2);
  if (off > ws_size) return;  // workspace too small: fail loudly (wrong output)

  unsigned short* Aim = qkv;  // im2col buffer aliases qkv (dead by layer 0)
  // Split-K partial 0 aliases qkv (dead after attn_fused_k consumes Q,K);
  // read by the immediately-following ln_fuse_k before the region's next
  // writer (next layer's qkv GEMM).
  float* pp0 = (float*)qkv;   // 19.27 <= 28.9 MB

  auto cvt = [&](const float* src, unsigned short* dst, size_t n) {
    int n4 = (int)(n / 4);
    cvt4_k<<<dim3((n4 + 255) / 256), dim3(256), 0, stream>>>(
        (const float4*)src, (ushort4*)dst, n4);
  };
  cvt(qkvw, Wq, (size_t)LL * 2304 * 768);
  cvt(projw, Wp, (size_t)LL * 768 * 768);
  cvt(fc1w, W1, (size_t)LL * 3072 * 768);
  cvt(fc2w, W2, (size_t)LL * 768 * 3072);
  cvt(patchw, Wpe, (size_t)768 * 768);

  // zero Vt's j in [196,224) pad once; layer GEMMs only write j < 196
  vtpad_k<<<dim3(BHH * 64 * 28 / 256), dim3(256), 0, stream>>>(Vt);

  im2col_k<<<dim3(MM * DD / 256), dim3(256), 0, stream>>>(x, Aim);
  // patch embed GEMM: h = Aim @ Wpe^T + patch_b + pos
  gemm64_bt<1><<<dim3(6, 98), dim3(256), 0, stream>>>(Aim, Wpe, patchb, pos, h, 768, 768);

  // layer 0 ln1 (wave-parallel)
  lnw_k<<<dim3(MM / 4), dim3(256), 0, stream>>>(h, ln1w, ln1b, y);

  for (int l = 0; l < LL; l++) {
    // qkv GEMM: Q,K -> qkv buffer; V -> Vt (transposed epilogue)
    gemm_bt<4><<<dim3(18, 49), dim3(256), 0, stream>>>(
        y, Wq + (size_t)l * 2304 * 768, qkvb + l * 2304, qkv, Vt, 768, 2304);
    attn_fused_k<<<dim3(BHH, 7), dim3(256), 0, stream>>>(qkv, Vt, o);
    // proj: 128x128 tile, split-K=2, fp32 partials (pp0 overwrites qkv region)
    gemm_sk<<<dim3(6, 49, 2), dim3(256), 0, stream>>>(
        o, Wp + (size_t)l * 768 * 768, projb + l * 768, pp0, pp1, 768, 768);
    // h += pp0+pp1; y = ln2(h)
    ln_fuse_k<0><<<dim3(MM / 4), dim3(256), 0, stream>>>(
        h, pp0, pp1, ln2w + l * 768, ln2b + l * 768, y);
    gemm_bt<3><<<dim3(24, 49), dim3(256), 0, stream>>>(
        y, W1 + (size_t)l * 3072 * 768, fc1b + l * 3072, g, nullptr, 768, 3072);
    // fc2: 128x128 tile, split-K=2, fp32 partials
    gemm_sk<<<dim3(6, 49, 2), dim3(256), 0, stream>>>(
        g, W2 + (size_t)l * 768 * 3072, fc2b + l * 768, pp0, pp1, 3072, 768);
    if (l + 1 < LL) {
      // h += pp0+pp1; y = ln1_{l+1}(h)
      ln_fuse_k<0><<<dim3(MM / 4), dim3(256), 0, stream>>>(
          h, pp0, pp1, ln1w + (l + 1) * 768, ln1b + (l + 1) * 768, y);
    } else {
      // final: out = lnf(h + pp0 + pp1), fp32
      ln_fuse_k<1><<<dim3(MM / 4), dim3(256), 0, stream>>>(
          h, pp0, pp1, lnfw, lnfb, d_out);
    }
  }
}